// Round 12
// baseline (108.628 us; speedup 1.0000x reference)
//
#include <hip/hip_runtime.h>
#include <math.h>

// ---------------- constants ----------------
#define NB 16384
#define DN 64
#define ST 68            // LDS row stride (16B-aligned rows)
// output offsets (floats)
#define OFF1 491520      // data_LiDAR
#define OFF2 983040      // HSI_A
#define OFF3 1966080     // HSI_Dn
#define OFF4 1968000     // LiDAR_A
#define OFF5 2951040     // LiDAR_Dn
#define OFF6 2952960     // output
// ws offsets (floats)
#define SPH_OFF   0
#define SPL_OFF   1048576
#define DSPH_OFF  1064960
#define DSPL_OFF  1069056
#define W12H_OFF  1069120
#define B12H_OFF  1071040
#define W12L_OFF  1071072
#define B12L_OFF  1071104
#define MH_OFF    1071136
#define B2H_OFF   1073056
#define ML_OFF    1073120
#define B2L_OFF   1075040
#define GH_OFF    1075104
#define GL_OFF    1078944
#define WF_OFF    1082784
#define BF_OFF    1083632
#define AH_OFF    1083648
#define AL_OFF    2132224

typedef const __attribute__((address_space(1))) void* gas_ptr;
typedef __attribute__((address_space(3))) void* las_ptr;

__device__ __forceinline__ float wredmax(float v) {
#pragma unroll
    for (int m = 32; m; m >>= 1) v = fmaxf(v, __shfl_xor(v, m, 64));
    return v;
}
__device__ __forceinline__ float wredsum(float v) {
#pragma unroll
    for (int m = 32; m; m >>= 1) v += __shfl_xor(v, m, 64);
    return v;
}

// ---- f4-vectorized chunk loader: xrow 16B-aligned.
template<int CH>
__device__ __forceinline__ void load_chunk(const float* __restrict__ xrow, float* __restrict__ x) {
    const int NQ = CH >> 2;
#pragma unroll
    for (int q = 0; q < NQ; ++q) {
        float4 v = *(const float4*)(xrow + 4 * q);
        x[4 * q] = v.x; x[4 * q + 1] = v.y; x[4 * q + 2] = v.z; x[4 * q + 3] = v.w;
    }
#pragma unroll
    for (int j = NQ * 4; j < CH; ++j) x[j] = xrow[j];
}

// y[o] = scale*(bias[o] + sum_c W[o*RS+c]*x[c]) for o in [o0,o0+PER) ∩ [0,OUTS)
template<int INS, int RS, int PER>
__device__ __forceinline__ void dlayer4(const float* __restrict__ W,
                                        const float* __restrict__ bias,
                                        const float* __restrict__ xb,
                                        float* __restrict__ yb,
                                        const int OUTS, const int o0,
                                        const float scale)
{
    float acc[PER];
#pragma unroll
    for (int k = 0; k < PER; ++k) {
        int oc = o0 + k; oc = oc < OUTS ? oc : OUTS - 1;
        acc[k] = bias ? bias[oc] : 0.0f;
    }
#pragma unroll
    for (int c0 = 0; c0 < INS; c0 += 16) {
        const int CHv = (INS - c0) < 16 ? (INS - c0) : 16;
        float x[16];
        if (CHv == 16) load_chunk<16>(xb + c0, x);
        else if (CHv == 15) load_chunk<15>(xb + c0, x);
        else if (CHv == 14) load_chunk<14>(xb + c0, x);
        else if (CHv == 13) load_chunk<13>(xb + c0, x);
        else if (CHv == 12) load_chunk<12>(xb + c0, x);
        else {
#pragma unroll
            for (int j = 0; j < 16; ++j) if (j < CHv) x[j] = xb[c0 + j];
        }
#pragma unroll
        for (int k = 0; k < PER; ++k) {
            int oc = o0 + k; oc = oc < OUTS ? oc : OUTS - 1;
            const float* Wr = W + oc * RS + c0;
            float a = acc[k];
#pragma unroll
            for (int j = 0; j < 16; ++j) if (j < CHv) a = fmaf(Wr[j], x[j], a);
            acc[k] = a;
        }
    }
#pragma unroll
    for (int k = 0; k < PER; ++k) {
        int o = o0 + k;
        if (o < OUTS) yb[o] = acc[k] * scale;
    }
}

// y[o] = scale*sum_c W[c*CS+o]*x[c] (+ bias AFTER scale)  (transposed weights)
template<int INS, int CS, int PER>
__device__ __forceinline__ void dlayerT4b(const float* __restrict__ W,
                                          const float* __restrict__ bias,
                                          const float* __restrict__ xb,
                                          float* __restrict__ yb,
                                          const int OUTS, const int o0,
                                          const float scale)
{
    float acc[PER];
#pragma unroll
    for (int k = 0; k < PER; ++k) acc[k] = 0.0f;
#pragma unroll
    for (int c0 = 0; c0 < INS; c0 += 16) {
        const int CHv = (INS - c0) < 16 ? (INS - c0) : 16;
        float x[16];
        if (CHv == 16) load_chunk<16>(xb + c0, x);
        else if (CHv == 12) load_chunk<12>(xb + c0, x);
        else {
#pragma unroll
            for (int j = 0; j < 16; ++j) if (j < CHv) x[j] = xb[c0 + j];
        }
#pragma unroll
        for (int j = 0; j < 16; ++j) {
            if (j < CHv) {
                const float* Wr = W + (c0 + j) * CS + o0;
#pragma unroll
                for (int k = 0; k < PER; ++k) acc[k] = fmaf(Wr[k], x[j], acc[k]);
            }
        }
    }
#pragma unroll
    for (int k = 0; k < PER; ++k) {
        int o = o0 + k;
        if (o < OUTS) yb[o] = bias ? (acc[k] * scale + bias[o]) : acc[k] * scale;
    }
}

// exp(S - max(S)) over a 64-wide row (f4); wave w covers cols 4w..4w+3 (16 waves).
__device__ __forceinline__ void softmax_exp4(const float* __restrict__ Sb,
                                             float* __restrict__ Qb,
                                             float* __restrict__ P,
                                             const int w, const int l)
{
    const float4* S4 = (const float4*)Sb;
    float4 m4 = S4[0];
#pragma unroll
    for (int q = 1; q < 16; ++q) {
        float4 v = S4[q];
        m4.x = fmaxf(m4.x, v.x); m4.y = fmaxf(m4.y, v.y);
        m4.z = fmaxf(m4.z, v.z); m4.w = fmaxf(m4.w, v.w);
    }
    const float mx = fmaxf(fmaxf(m4.x, m4.y), fmaxf(m4.z, m4.w));
    float4 sv = S4[w];
    float4 e;
    e.x = __expf(sv.x - mx); e.y = __expf(sv.y - mx);
    e.z = __expf(sv.z - mx); e.w = __expf(sv.w - mx);
    ((float4*)Qb)[w] = e;
    P[w * 64 + l] = (e.x + e.y) + (e.z + e.w);
}

// 1/sum over 16 per-wave partials
__device__ __forceinline__ float inv16(const float* __restrict__ P, const int l)
{
    float s0 = P[l], s1 = P[64 + l], s2 = P[128 + l], s3 = P[192 + l];
#pragma unroll
    for (int g = 4; g < 16; g += 4) {
        s0 += P[g * 64 + l];
        s1 += P[(g + 1) * 64 + l];
        s2 += P[(g + 2) * 64 + l];
        s3 += P[(g + 3) * 64 + l];
    }
    return 1.0f / ((s0 + s1) + (s2 + s3));
}

// ---------------- Kernel A: patch attention (4 items/block; dict grid merged) ----------------
__global__ __launch_bounds__(256) void patch_attend_kernel(
    const float* __restrict__ patchH, const float* __restrict__ xH,
    const float* __restrict__ patchL, const float* __restrict__ xL,
    float* __restrict__ spH, float* __restrict__ spL,
    const float* __restrict__ dpH, const float* __restrict__ dxH,
    const float* __restrict__ dpL, const float* __restrict__ dxL,
    float* __restrict__ dspH, float* __restrict__ dspL)
{
    __shared__ __align__(16) float ph[4 * 3087];
    __shared__ __align__(16) float pl_[4 * 49];
    __shared__ __align__(16) float xh[4 * 63];
    __shared__ float xls[4];
    __shared__ float pw[4 * 49];

    const int tid = threadIdx.x;
    const bool isD = blockIdx.x >= (NB / 4);
    const int b0 = (isD ? (blockIdx.x - NB / 4) : blockIdx.x) * 4;
    const float* PH = isD ? dpH : patchH;
    const float* XH = isD ? dxH : xH;
    const float* PL = isD ? dpL : patchL;
    const float* XL = isD ? dxL : xL;
    float* SH = isD ? dspH : spH;
    float* SL = isD ? dspL : spL;
    {
        const float4* s4 = (const float4*)(PH + (size_t)b0 * 3087);
        float4* d4 = (float4*)ph;
        for (int i = tid; i < 3087; i += 256) {
            __builtin_amdgcn_global_load_lds((gas_ptr)(const void*)(s4 + i),
                                             (las_ptr)(void*)(d4 + i), 16, 0, 0);
        }
        if (tid < 49) ((float4*)pl_)[tid] = ((const float4*)(PL + (size_t)b0 * 49))[tid];
        if (tid >= 64 && tid < 127) ((float4*)xh)[tid - 64] = ((const float4*)(XH + (size_t)b0 * 63))[tid - 64];
        if (tid == 255) *((float4*)xls) = *((const float4*)(XL + b0));
    }
    asm volatile("s_waitcnt vmcnt(0)" ::: "memory");
    __syncthreads();

    const int w = tid >> 6, l = tid & 63;
    const float* phw = ph + w * 3087;
    const float* plw = pl_ + w * 49;
    const float* xhw = xh + w * 63;
    const float xlw = xls[w];

    float eh = -INFINITY, el = -INFINITY;
    if (l < 49) {
        float acc = 0.f;
#pragma unroll
        for (int c = 0; c < 63; ++c) {
            float t = xhw[c] - phw[c * 49 + l] + 1e-6f;
            acc = fmaf(t, t, acc);
        }
        eh = __expf(-sqrtf(acc));
        float tl = xlw - plw[l] + 1e-6f;
        el = __expf(-fabsf(tl));
    }
    float mh = wredmax(eh), ml = wredmax(el);
    float qh = (l < 49) ? __expf(eh - mh) : 0.f;
    float ql = (l < 49) ? __expf(el - ml) : 0.f;
    float sh = wredsum(qh);
    float sl = wredsum(ql);
    if (l < 49) pw[w * 49 + l] = qh / sh;
    float spl_v = wredsum((l < 49) ? plw[l] * (ql / sl) : 0.f);
    if (l == 0) SL[b0 + w] = spl_v;
    __syncthreads();
    if (l < 63) {
        float acc = 0.f;
        const float* pww = pw + w * 49;
#pragma unroll
        for (int s = 0; s < 49; ++s) acc = fmaf(phw[l * 49 + s], pww[s], acc);
        SH[(size_t)(b0 + w) * 64 + l] = acc;   // stride-64 rows (col 63 unused)
    }
}

// ---------------- Kernel C: dictionary chain + fused-weight precompute ----------------
// Produces: W12H/b12H (63->30 fused lin1), W12L/b12L (1->30 fused lin2),
// M/bias2 (30->64 fused attn-score), G (64->60 fused PV+feat), Wf/bf (120->7
// fused output head), and Dn = m*Dp.
__global__ __launch_bounds__(1024) void dict_chain_kernel(
    const float* __restrict__ dsph, const float* __restrict__ dspl,
    const float* __restrict__ w1_1, const float* __restrict__ b1_1,
    const float* __restrict__ w1_2, const float* __restrict__ b1_2,
    const float* __restrict__ w2_1, const float* __restrict__ b2_1,
    const float* __restrict__ w2_2, const float* __restrict__ b2_2,
    const float* __restrict__ wa1, const float* __restrict__ ba1,
    const float* __restrict__ wa2, const float* __restrict__ ba2,
    const float* __restrict__ wo1, const float* __restrict__ bo1,
    const float* __restrict__ wo2, const float* __restrict__ bo2,
    float* __restrict__ w12H, float* __restrict__ b12H,
    float* __restrict__ w12L, float* __restrict__ b12L,
    float* __restrict__ mH, float* __restrict__ b2H,
    float* __restrict__ mL, float* __restrict__ b2L,
    float* __restrict__ gH, float* __restrict__ gL,
    float* __restrict__ wf, float* __restrict__ bf,
    const int* __restrict__ mI, float* __restrict__ out)
{
    __shared__ __align__(16) float HA[64 * ST];
    __shared__ __align__(16) float HB[64 * ST];
    __shared__ __align__(16) float LA[64 * ST];
    __shared__ __align__(16) float LB[64 * ST];
    __shared__ float W12s[1984];   // [0,1890) W12H; [1890,1920) b12H; [1920,1950) W12L; [1950,1980) b12L

    const int tid = threadIdx.x;
    const int w = __builtin_amdgcn_readfirstlane(tid >> 6);
    const int l = tid & 63;
    const float mf = (float)(*mI);
    const float xl = dspl[l];

    // P0: stage dsp_H (stride-64 rows -> ST rows)
    {
        int r = tid >> 4, q = tid & 15;
        *(float4*)(HA + r * ST + 4 * q) = ((const float4*)dsph)[tid];
    }
    // P1: fused-weight precomputes (independent of staging)
    for (int i = tid; i < 1890; i += 1024) {
        int o = i / 63, c = i - o * 63;
        float s = 0.f;
        for (int k = 0; k < 45; ++k) s = fmaf(w1_2[o * 45 + k], w1_1[k * 63 + c], s);
        W12s[i] = s; w12H[i] = s;
    }
    if (tid < 30) {
        float s = b1_2[tid];
        for (int k = 0; k < 45; ++k) s = fmaf(w1_2[tid * 45 + k], b1_1[k], s);
        W12s[1890 + tid] = s; b12H[tid] = s;
    }
    if (tid >= 32 && tid < 62) {
        int o = tid - 32;
        float s = 0.f;
        for (int k = 0; k < 15; ++k) s = fmaf(w2_2[o * 15 + k], w2_1[k], s);
        W12s[1920 + o] = s; w12L[o] = s;
    }
    if (tid >= 64 && tid < 94) {
        int o = tid - 64;
        float s = b2_2[o];
        for (int k = 0; k < 15; ++k) s = fmaf(w2_2[o * 15 + k], b2_1[k], s);
        W12s[1950 + o] = s; b12L[o] = s;
    }
    for (int i = tid; i < 840; i += 1024) {
        int o = i / 120, c = i - o * 120;
        float s = 0.f;
        for (int d = 0; d < 60; ++d) s = fmaf(wo2[o * 60 + d], wo1[d * 120 + c], s);
        wf[i] = s;
    }
    if (tid >= 96 && tid < 103) {
        int o = tid - 96;
        float s = bo2[o];
        for (int d = 0; d < 60; ++d) s = fmaf(wo2[o * 60 + d], bo1[d], s);
        bf[o] = s;
    }
    __syncthreads();
    // P2: Dp (fused 63->30 / 1->30); HB := Dp_H, LB := Dp_L
    dlayer4<63, 63, 2>(W12s, W12s + 1890, HA + l * ST, HB + l * ST, 30, w * 2, 1.0f);
#pragma unroll
    for (int k = 0; k < 2; ++k) {
        int o = w * 2 + k;
        if (o < 30) LB[l * ST + o] = fmaf(W12s[1920 + o], xl, W12s[1950 + o]);
    }
    __syncthreads();
    // P3: Dn = m*Dp  +  d2 = wa2(Dp): HA := d2H, LA := d2L
    for (int i = tid; i < 1920; i += 1024) {
        int c = i >> 6, j = i & 63;
        out[OFF3 + i] = mf * HB[j * ST + c];
        out[OFF5 + i] = mf * LB[j * ST + c];
    }
    dlayer4<30, 30, 4>(wa2, ba2, HB + l * ST, HA + l * ST, 60, w * 4, 1.0f);
    dlayer4<30, 30, 4>(wa2, ba2, LB + l * ST, LA + l * ST, 60, w * 4, 1.0f);
    __syncthreads();
    // P4: M = d2 @ wa1 (+bias2 = d2 @ ba1), G = Dp @ wa1^T  -> ws directly
    dlayerT4b<60, 30, 2>(wa1, nullptr, HA + l * ST, mH + l * 30, 30, w * 2, 1.0f);
    dlayerT4b<60, 30, 2>(wa1, nullptr, LA + l * ST, mL + l * 30, 30, w * 2, 1.0f);
    dlayer4<30, 30, 4>(wa1, nullptr, HB + l * ST, gH + l * 60, 60, w * 4, 1.0f);
    dlayer4<30, 30, 4>(wa1, nullptr, LB + l * ST, gL + l * 60, 60, w * 4, 1.0f);
    if (tid < 64) {
        float sH = 0.f, sL = 0.f;
        for (int d = 0; d < 60; ++d) {
            sH = fmaf(HA[tid * ST + d], ba1[d], sH);
            sL = fmaf(LA[tid * ST + d], ba1[d], sL);
        }
        b2H[tid] = sH; b2L[tid] = sL;
    }
}

// ---------------- Kernel B: per-item chain (64 items/block, 16 waves, fused layers) ----------------
__global__ __launch_bounds__(1024) void chain_kernel(
    const float* __restrict__ spH, const float* __restrict__ spL,
    const float* __restrict__ w12H, const float* __restrict__ b12H,
    const float* __restrict__ w12L, const float* __restrict__ b12L,
    const float* __restrict__ mH, const float* __restrict__ b2H,
    const float* __restrict__ mL, const float* __restrict__ b2L,
    const float* __restrict__ gH, const float* __restrict__ gL,
    const float* __restrict__ ba1,
    const float* __restrict__ wf, const float* __restrict__ bf,
    const int* __restrict__ mI,
    float* __restrict__ out, float* __restrict__ aH, float* __restrict__ aL)
{
    __shared__ __align__(16) float HA[64 * ST];
    __shared__ __align__(16) float HB[64 * ST];
    __shared__ __align__(16) float LA[64 * ST];
    __shared__ __align__(16) float LB[64 * ST];
    __shared__ float PH[16 * 64], PL[16 * 64];

    const int tid = threadIdx.x;
    const int w = __builtin_amdgcn_readfirstlane(tid >> 6);
    const int l = tid & 63;
    const int b0 = blockIdx.x * 64;
    const int b = b0 + l;
    const float mf = (float)(*mI);
    const float xl = spL[b];

    {
        int r = tid >> 4, q = tid & 15;
        *(float4*)(HA + r * ST + 4 * q) = ((const float4*)(spH + (size_t)b0 * 64))[tid];
    }
    __syncthreads();

    // s12: H 63->30 (fused lin1) ; L 1->30 (fused lin2)
    dlayer4<63, 63, 2>(w12H, b12H, HA + l * ST, HB + l * ST, 30, w * 2, 1.0f);
#pragma unroll
    for (int k = 0; k < 2; ++k) {
        int o = w * 2 + k;
        if (o < 30) LA[l * ST + o] = fmaf(w12L[o], xl, b12L[o]);
    }
    __syncthreads();
    // data copies + s34: S = M @ data + bias2 (30->64)
    for (int i = tid; i < 1920; i += 1024) {
        int r = i / 30, c = i - r * 30;
        out[(size_t)b0 * 30 + i] = HB[r * ST + c];
        out[OFF1 + (size_t)b0 * 30 + i] = LA[r * ST + c];
    }
    dlayer4<30, 30, 4>(mH, b2H, HB + l * ST, HA + l * ST, 64, w * 4, 1.0f);
    dlayer4<30, 30, 4>(mL, b2L, LA + l * ST, LB + l * ST, 64, w * 4, 1.0f);
    __syncthreads();
    // softmax exp
    softmax_exp4(HA + l * ST, HB + l * ST, PH, w, l);
    softmax_exp4(LB + l * ST, LA + l * ST, PL, w, l);
    __syncthreads();
    // A-matrix writes (only consumed when m != 1)
    if (mf != 1.0f) {
        for (int i = tid; i < 4096; i += 1024) {
            int r = i >> 6, j = i & 63;
            aH[(size_t)b0 * 64 + i] = HB[r * ST + j] * inv16(PH, r);
            aL[(size_t)b0 * 64 + i] = LA[r * ST + j] * inv16(PL, r);
        }
    }
    // fused PV+feat: A60 = inv*(P @ G) + ba1  (64->60)
    {
        const float invH = inv16(PH, l);
        const float invL = inv16(PL, l);
        dlayerT4b<64, 60, 4>(gH, ba1, HB + l * ST, HA + l * ST, 60, w * 4, invH);
        dlayerT4b<64, 60, 4>(gL, ba1, LA + l * ST, LB + l * ST, 60, w * 4, invL);
    }
    __syncthreads();
    // A60 copies + fused output head: out7 = Wf @ [A60l ; A60h] + bf
    for (int i = tid; i < 3840; i += 1024) {
        int r = i / 60, c = i - r * 60;
        out[OFF2 + (size_t)b0 * 60 + i] = HA[r * ST + c];
        out[OFF4 + (size_t)b0 * 60 + i] = LB[r * ST + c];
    }
    if (w < 7) {
        float a = bf[w];
        const float* Wr = wf + w * 120;
#pragma unroll
        for (int c0 = 0; c0 < 60; c0 += 16) {
            const int CH = (60 - c0) < 16 ? (60 - c0) : 16;
            float x[16];
            if (CH == 16) load_chunk<16>(LB + l * ST + c0, x);
            else load_chunk<12>(LB + l * ST + c0, x);
#pragma unroll
            for (int j = 0; j < 16; ++j) if (j < CH) a = fmaf(Wr[c0 + j], x[j], a);
        }
#pragma unroll
        for (int c0 = 0; c0 < 60; c0 += 16) {
            const int CH = (60 - c0) < 16 ? (60 - c0) : 16;
            float x[16];
            if (CH == 16) load_chunk<16>(HA + l * ST + c0, x);
            else load_chunk<12>(HA + l * ST + c0, x);
#pragma unroll
            for (int j = 0; j < 16; ++j) if (j < CH) a = fmaf(Wr[60 + c0 + j], x[j], a);
        }
        out[OFF6 + (size_t)b * 7 + w] = a;
    }
}

// ---------------- Kernel D: momentum update (early-exit when m == 1) ----------------
// Dn already holds m*Dp (dict_chain); add (1-m) * data^T @ A via atomics.
__global__ __launch_bounds__(256) void momentum_kernel(
    const float* __restrict__ dataH, const float* __restrict__ dataL,
    const float* __restrict__ aH, const float* __restrict__ aL,
    const int* __restrict__ mI, float* __restrict__ out)
{
    const float mf = (float)(*mI);
    if (mf == 1.0f) return;
    const int tid = threadIdx.x;
    const int chunk = blockIdx.x & 63;
    const int mod = blockIdx.x >> 6;
    const float* data = mod ? dataL : dataH;
    const float* A = mod ? aL : aH;
    float* D = out + (mod ? OFF5 : OFF3);
    const int b0 = chunk * 256;
    const int j = tid & 63;
    const int g = tid >> 6;
    float acc[8];
#pragma unroll
    for (int k = 0; k < 8; ++k) acc[k] = 0.f;
    for (int bb = 0; bb < 256; ++bb) {
        float a = A[(size_t)(b0 + bb) * 64 + j];
#pragma unroll
        for (int k = 0; k < 8; ++k) {
            int c = g + 4 * k; c = c < 30 ? c : 29;
            acc[k] = fmaf(data[(size_t)(b0 + bb) * 30 + c], a, acc[k]);
        }
    }
    const float s = 1.0f - mf;
#pragma unroll
    for (int k = 0; k < 8; ++k) {
        int c = g + 4 * k;
        if (c < 30) atomicAdd(&D[c * 64 + j], s * acc[k]);
    }
}

extern "C" void kernel_launch(void* const* d_in, const int* in_sizes, int n_in,
                              void* d_out, int out_size, void* d_ws, size_t ws_size,
                              hipStream_t stream) {
    const float* H_HSI        = (const float*)d_in[0];
    const float* H_LiDAR      = (const float*)d_in[1];
    const float* HSI_D        = (const float*)d_in[2];
    const float* LiDAR_D      = (const float*)d_in[3];
    const float* Patch_HSI    = (const float*)d_in[4];
    const float* Patch_LiDAR  = (const float*)d_in[5];
    const float* D_Patch_HSI  = (const float*)d_in[6];
    const float* D_Patch_LiDAR= (const float*)d_in[7];
    const int*   mI           = (const int*)d_in[9];
    const float* w1_1 = (const float*)d_in[12];
    const float* b1_1 = (const float*)d_in[13];
    const float* w1_2 = (const float*)d_in[14];
    const float* b1_2 = (const float*)d_in[15];
    const float* w2_1 = (const float*)d_in[16];
    const float* b2_1 = (const float*)d_in[17];
    const float* w2_2 = (const float*)d_in[18];
    const float* b2_2 = (const float*)d_in[19];
    const float* wa1  = (const float*)d_in[20];
    const float* ba1  = (const float*)d_in[21];
    const float* wa2  = (const float*)d_in[22];
    const float* ba2  = (const float*)d_in[23];
    const float* wo1  = (const float*)d_in[24];
    const float* bo1  = (const float*)d_in[25];
    const float* wo2  = (const float*)d_in[26];
    const float* bo2  = (const float*)d_in[27];

    float* out = (float*)d_out;
    float* ws  = (float*)d_ws;

    patch_attend_kernel<<<NB / 4 + DN / 4, 256, 0, stream>>>(
        Patch_HSI, H_HSI, Patch_LiDAR, H_LiDAR, ws + SPH_OFF, ws + SPL_OFF,
        D_Patch_HSI, HSI_D, D_Patch_LiDAR, LiDAR_D, ws + DSPH_OFF, ws + DSPL_OFF);
    dict_chain_kernel<<<1, 1024, 0, stream>>>(
        ws + DSPH_OFF, ws + DSPL_OFF,
        w1_1, b1_1, w1_2, b1_2, w2_1, b2_1, w2_2, b2_2,
        wa1, ba1, wa2, ba2, wo1, bo1, wo2, bo2,
        ws + W12H_OFF, ws + B12H_OFF, ws + W12L_OFF, ws + B12L_OFF,
        ws + MH_OFF, ws + B2H_OFF, ws + ML_OFF, ws + B2L_OFF,
        ws + GH_OFF, ws + GL_OFF, ws + WF_OFF, ws + BF_OFF,
        mI, out);
    chain_kernel<<<NB / 64, 1024, 0, stream>>>(
        ws + SPH_OFF, ws + SPL_OFF,
        ws + W12H_OFF, ws + B12H_OFF, ws + W12L_OFF, ws + B12L_OFF,
        ws + MH_OFF, ws + B2H_OFF, ws + ML_OFF, ws + B2L_OFF,
        ws + GH_OFF, ws + GL_OFF, ba1, ws + WF_OFF, ws + BF_OFF,
        mI, out, ws + AH_OFF, ws + AL_OFF);
    momentum_kernel<<<128, 256, 0, stream>>>(
        out, out + OFF1, ws + AH_OFF, ws + AL_OFF, mI, out);
}

// Round 13
// 101.049 us; speedup vs baseline: 1.0750x; 1.0750x over previous
//
#include <hip/hip_runtime.h>
#include <math.h>

// ---------------- constants ----------------
#define NB 16384
#define DN 64
#define ST 68            // LDS row stride (16B-aligned rows)
// output offsets (floats)
#define OFF1 491520      // data_LiDAR
#define OFF2 983040      // HSI_A
#define OFF3 1966080     // HSI_Dn
#define OFF4 1968000     // LiDAR_A
#define OFF5 2951040     // LiDAR_Dn
#define OFF6 2952960     // output
// ws offsets (floats)
#define SPH_OFF   0
#define SPL_OFF   1048576
#define DSPH_OFF  1064960
#define DSPL_OFF  1069056
#define W12H_OFF  1069120
#define B12H_OFF  1071040
#define W12L_OFF  1071072
#define B12L_OFF  1071104
#define MH_OFF    1071136
#define B2H_OFF   1073056
#define ML_OFF    1073120
#define B2L_OFF   1075040
#define GH_OFF    1075104
#define GL_OFF    1078944
#define WF_OFF    1082784
#define BF_OFF    1083632
#define AH_OFF    1083648
#define AL_OFF    2132224

typedef const __attribute__((address_space(1))) void* gas_ptr;
typedef __attribute__((address_space(3))) void* las_ptr;

__device__ __forceinline__ float wredmax(float v) {
#pragma unroll
    for (int m = 32; m; m >>= 1) v = fmaxf(v, __shfl_xor(v, m, 64));
    return v;
}
__device__ __forceinline__ float wredsum(float v) {
#pragma unroll
    for (int m = 32; m; m >>= 1) v += __shfl_xor(v, m, 64);
    return v;
}

// ---- f4-vectorized chunk loader: xrow 16B-aligned.
template<int CH>
__device__ __forceinline__ void load_chunk(const float* __restrict__ xrow, float* __restrict__ x) {
    const int NQ = CH >> 2;
#pragma unroll
    for (int q = 0; q < NQ; ++q) {
        float4 v = *(const float4*)(xrow + 4 * q);
        x[4 * q] = v.x; x[4 * q + 1] = v.y; x[4 * q + 2] = v.z; x[4 * q + 3] = v.w;
    }
#pragma unroll
    for (int j = NQ * 4; j < CH; ++j) x[j] = xrow[j];
}

// y[o] = scale*(bias[o] + sum_c W[o*RS+c]*x[c]) for o in [o0,o0+PER) ∩ [0,OUTS)
template<int INS, int RS, int PER>
__device__ __forceinline__ void dlayer4(const float* __restrict__ W,
                                        const float* __restrict__ bias,
                                        const float* __restrict__ xb,
                                        float* __restrict__ yb,
                                        const int OUTS, const int o0,
                                        const float scale)
{
    float acc[PER];
#pragma unroll
    for (int k = 0; k < PER; ++k) {
        int oc = o0 + k; oc = oc < OUTS ? oc : OUTS - 1;
        acc[k] = bias ? bias[oc] : 0.0f;
    }
#pragma unroll
    for (int c0 = 0; c0 < INS; c0 += 16) {
        const int CHv = (INS - c0) < 16 ? (INS - c0) : 16;
        float x[16];
        if (CHv == 16) load_chunk<16>(xb + c0, x);
        else if (CHv == 15) load_chunk<15>(xb + c0, x);
        else if (CHv == 14) load_chunk<14>(xb + c0, x);
        else if (CHv == 13) load_chunk<13>(xb + c0, x);
        else if (CHv == 12) load_chunk<12>(xb + c0, x);
        else {
#pragma unroll
            for (int j = 0; j < 16; ++j) if (j < CHv) x[j] = xb[c0 + j];
        }
#pragma unroll
        for (int k = 0; k < PER; ++k) {
            int oc = o0 + k; oc = oc < OUTS ? oc : OUTS - 1;
            const float* Wr = W + oc * RS + c0;
            float a = acc[k];
#pragma unroll
            for (int j = 0; j < 16; ++j) if (j < CHv) a = fmaf(Wr[j], x[j], a);
            acc[k] = a;
        }
    }
#pragma unroll
    for (int k = 0; k < PER; ++k) {
        int o = o0 + k;
        if (o < OUTS) yb[o] = acc[k] * scale;
    }
}

// y[o] = scale*sum_c W[c*CS+o]*x[c] (+ bias AFTER scale)  (transposed weights)
template<int INS, int CS, int PER>
__device__ __forceinline__ void dlayerT4b(const float* __restrict__ W,
                                          const float* __restrict__ bias,
                                          const float* __restrict__ xb,
                                          float* __restrict__ yb,
                                          const int OUTS, const int o0,
                                          const float scale)
{
    float acc[PER];
#pragma unroll
    for (int k = 0; k < PER; ++k) acc[k] = 0.0f;
#pragma unroll
    for (int c0 = 0; c0 < INS; c0 += 16) {
        const int CHv = (INS - c0) < 16 ? (INS - c0) : 16;
        float x[16];
        if (CHv == 16) load_chunk<16>(xb + c0, x);
        else if (CHv == 12) load_chunk<12>(xb + c0, x);
        else {
#pragma unroll
            for (int j = 0; j < 16; ++j) if (j < CHv) x[j] = xb[c0 + j];
        }
#pragma unroll
        for (int j = 0; j < 16; ++j) {
            if (j < CHv) {
                const float* Wr = W + (c0 + j) * CS + o0;
#pragma unroll
                for (int k = 0; k < PER; ++k) acc[k] = fmaf(Wr[k], x[j], acc[k]);
            }
        }
    }
#pragma unroll
    for (int k = 0; k < PER; ++k) {
        int o = o0 + k;
        if (o < OUTS) yb[o] = bias ? (acc[k] * scale + bias[o]) : acc[k] * scale;
    }
}

// exp(S - max(S)) over a 64-wide row (f4); wave w covers cols 4w..4w+3 (16 waves).
__device__ __forceinline__ void softmax_exp4(const float* __restrict__ Sb,
                                             float* __restrict__ Qb,
                                             float* __restrict__ P,
                                             const int w, const int l)
{
    const float4* S4 = (const float4*)Sb;
    float4 m4 = S4[0];
#pragma unroll
    for (int q = 1; q < 16; ++q) {
        float4 v = S4[q];
        m4.x = fmaxf(m4.x, v.x); m4.y = fmaxf(m4.y, v.y);
        m4.z = fmaxf(m4.z, v.z); m4.w = fmaxf(m4.w, v.w);
    }
    const float mx = fmaxf(fmaxf(m4.x, m4.y), fmaxf(m4.z, m4.w));
    float4 sv = S4[w];
    float4 e;
    e.x = __expf(sv.x - mx); e.y = __expf(sv.y - mx);
    e.z = __expf(sv.z - mx); e.w = __expf(sv.w - mx);
    ((float4*)Qb)[w] = e;
    P[w * 64 + l] = (e.x + e.y) + (e.z + e.w);
}

// 1/sum over 16 per-wave partials
__device__ __forceinline__ float inv16(const float* __restrict__ P, const int l)
{
    float s0 = P[l], s1 = P[64 + l], s2 = P[128 + l], s3 = P[192 + l];
#pragma unroll
    for (int g = 4; g < 16; g += 4) {
        s0 += P[g * 64 + l];
        s1 += P[(g + 1) * 64 + l];
        s2 += P[(g + 2) * 64 + l];
        s3 += P[(g + 3) * 64 + l];
    }
    return 1.0f / ((s0 + s1) + (s2 + s3));
}

// ---------------- Kernel A: patch attention (4 items/block; dict grid merged;
// 2 trailing fusion blocks precompute fused weight products into ws) ----------------
__global__ __launch_bounds__(256) void patch_attend_kernel(
    const float* __restrict__ patchH, const float* __restrict__ xH,
    const float* __restrict__ patchL, const float* __restrict__ xL,
    float* __restrict__ spH, float* __restrict__ spL,
    const float* __restrict__ dpH, const float* __restrict__ dxH,
    const float* __restrict__ dpL, const float* __restrict__ dxL,
    float* __restrict__ dspH, float* __restrict__ dspL,
    const float* __restrict__ w1_1, const float* __restrict__ b1_1,
    const float* __restrict__ w1_2, const float* __restrict__ b1_2,
    const float* __restrict__ w2_1, const float* __restrict__ b2_1,
    const float* __restrict__ w2_2, const float* __restrict__ b2_2,
    const float* __restrict__ wo1, const float* __restrict__ bo1,
    const float* __restrict__ wo2, const float* __restrict__ bo2,
    float* __restrict__ w12H, float* __restrict__ b12H,
    float* __restrict__ w12L, float* __restrict__ b12L,
    float* __restrict__ wf, float* __restrict__ bf)
{
    const int tid = threadIdx.x;

    // ---- fusion blocks: weight-only precompute, fully independent of patch data
    if (blockIdx.x >= (NB / 4 + DN / 4)) {
        const int fb = blockIdx.x - (NB / 4 + DN / 4);
        if (fb == 0) {
            for (int i = tid; i < 1890; i += 256) {
                int o = i / 63, c = i - o * 63;
                float s = 0.f;
#pragma unroll
                for (int k = 0; k < 45; ++k) s = fmaf(w1_2[o * 45 + k], w1_1[k * 63 + c], s);
                w12H[i] = s;
            }
            if (tid < 30) {
                float s = b1_2[tid];
#pragma unroll
                for (int k = 0; k < 45; ++k) s = fmaf(w1_2[tid * 45 + k], b1_1[k], s);
                b12H[tid] = s;
            } else if (tid >= 32 && tid < 62) {
                int o = tid - 32;
                float s = 0.f;
#pragma unroll
                for (int k = 0; k < 15; ++k) s = fmaf(w2_2[o * 15 + k], w2_1[k], s);
                w12L[o] = s;
            } else if (tid >= 64 && tid < 94) {
                int o = tid - 64;
                float s = b2_2[o];
#pragma unroll
                for (int k = 0; k < 15; ++k) s = fmaf(w2_2[o * 15 + k], b2_1[k], s);
                b12L[o] = s;
            }
        } else {
            for (int i = tid; i < 840; i += 256) {
                int o = i / 120, c = i - o * 120;
                float s = 0.f;
#pragma unroll
                for (int d = 0; d < 60; ++d) s = fmaf(wo2[o * 60 + d], wo1[d * 120 + c], s);
                wf[i] = s;
            }
            if (tid < 7) {
                float s = bo2[tid];
#pragma unroll
                for (int d = 0; d < 60; ++d) s = fmaf(wo2[tid * 60 + d], bo1[d], s);
                bf[tid] = s;
            }
        }
        return;
    }

    __shared__ __align__(16) float ph[4 * 3087];
    __shared__ __align__(16) float pl_[4 * 49];
    __shared__ __align__(16) float xh[4 * 63];
    __shared__ float xls[4];
    __shared__ float pw[4 * 49];

    const bool isD = blockIdx.x >= (NB / 4);
    const int b0 = (isD ? (blockIdx.x - NB / 4) : blockIdx.x) * 4;
    const float* PH = isD ? dpH : patchH;
    const float* XH = isD ? dxH : xH;
    const float* PL = isD ? dpL : patchL;
    const float* XL = isD ? dxL : xL;
    float* SH = isD ? dspH : spH;
    float* SL = isD ? dspL : spL;
    {
        const float4* s4 = (const float4*)(PH + (size_t)b0 * 3087);
        float4* d4 = (float4*)ph;
        for (int i = tid; i < 3087; i += 256) {
            __builtin_amdgcn_global_load_lds((gas_ptr)(const void*)(s4 + i),
                                             (las_ptr)(void*)(d4 + i), 16, 0, 0);
        }
        if (tid < 49) ((float4*)pl_)[tid] = ((const float4*)(PL + (size_t)b0 * 49))[tid];
        if (tid >= 64 && tid < 127) ((float4*)xh)[tid - 64] = ((const float4*)(XH + (size_t)b0 * 63))[tid - 64];
        if (tid == 255) *((float4*)xls) = *((const float4*)(XL + b0));
    }
    asm volatile("s_waitcnt vmcnt(0)" ::: "memory");
    __syncthreads();

    const int w = tid >> 6, l = tid & 63;
    const float* phw = ph + w * 3087;
    const float* plw = pl_ + w * 49;
    const float* xhw = xh + w * 63;
    const float xlw = xls[w];

    float eh = -INFINITY, el = -INFINITY;
    if (l < 49) {
        float acc = 0.f;
#pragma unroll
        for (int c = 0; c < 63; ++c) {
            float t = xhw[c] - phw[c * 49 + l] + 1e-6f;
            acc = fmaf(t, t, acc);
        }
        eh = __expf(-sqrtf(acc));
        float tl = xlw - plw[l] + 1e-6f;
        el = __expf(-fabsf(tl));
    }
    float mh = wredmax(eh), ml = wredmax(el);
    float qh = (l < 49) ? __expf(eh - mh) : 0.f;
    float ql = (l < 49) ? __expf(el - ml) : 0.f;
    float sh = wredsum(qh);
    float sl = wredsum(ql);
    if (l < 49) pw[w * 49 + l] = qh / sh;
    float spl_v = wredsum((l < 49) ? plw[l] * (ql / sl) : 0.f);
    if (l == 0) SL[b0 + w] = spl_v;
    __syncthreads();
    if (l < 63) {
        float acc = 0.f;
        const float* pww = pw + w * 49;
#pragma unroll
        for (int s = 0; s < 49; ++s) acc = fmaf(phw[l * 49 + s], pww[s], acc);
        SH[(size_t)(b0 + w) * 64 + l] = acc;   // stride-64 rows (col 63 unused)
    }
}

// ---------------- Kernel C: dictionary chain (fused weights from ws) ----------------
__global__ __launch_bounds__(1024) void dict_chain_kernel(
    const float* __restrict__ dsph, const float* __restrict__ dspl,
    const float* __restrict__ w12H, const float* __restrict__ b12H,
    const float* __restrict__ w12L, const float* __restrict__ b12L,
    const float* __restrict__ wa1, const float* __restrict__ ba1,
    const float* __restrict__ wa2, const float* __restrict__ ba2,
    float* __restrict__ mH, float* __restrict__ b2H,
    float* __restrict__ mL, float* __restrict__ b2L,
    float* __restrict__ gH, float* __restrict__ gL,
    const int* __restrict__ mI, float* __restrict__ out)
{
    __shared__ __align__(16) float HA[64 * ST];
    __shared__ __align__(16) float HB[64 * ST];
    __shared__ __align__(16) float LA[64 * ST];
    __shared__ __align__(16) float LB[64 * ST];

    const int tid = threadIdx.x;
    const int w = __builtin_amdgcn_readfirstlane(tid >> 6);
    const int l = tid & 63;
    const float mf = (float)(*mI);
    const float xl = dspl[l];

    // stage dsp_H (stride-64 rows -> ST rows)
    {
        int r = tid >> 4, q = tid & 15;
        *(float4*)(HA + r * ST + 4 * q) = ((const float4*)dsph)[tid];
    }
    __syncthreads();
    // P2: Dp (fused 63->30 / 1->30); HB := Dp_H, LB := Dp_L
    dlayer4<63, 63, 2>(w12H, b12H, HA + l * ST, HB + l * ST, 30, w * 2, 1.0f);
#pragma unroll
    for (int k = 0; k < 2; ++k) {
        int o = w * 2 + k;
        if (o < 30) LB[l * ST + o] = fmaf(w12L[o], xl, b12L[o]);
    }
    __syncthreads();
    // P3: Dn = m*Dp  +  d2 = wa2(Dp): HA := d2H, LA := d2L
    for (int i = tid; i < 1920; i += 1024) {
        int c = i >> 6, j = i & 63;
        out[OFF3 + i] = mf * HB[j * ST + c];
        out[OFF5 + i] = mf * LB[j * ST + c];
    }
    dlayer4<30, 30, 4>(wa2, ba2, HB + l * ST, HA + l * ST, 60, w * 4, 1.0f);
    dlayer4<30, 30, 4>(wa2, ba2, LB + l * ST, LA + l * ST, 60, w * 4, 1.0f);
    __syncthreads();
    // P4: M = d2 @ wa1 (+bias2 = d2 @ ba1), G = Dp @ wa1^T  -> ws directly
    dlayerT4b<60, 30, 2>(wa1, nullptr, HA + l * ST, mH + l * 30, 30, w * 2, 1.0f);
    dlayerT4b<60, 30, 2>(wa1, nullptr, LA + l * ST, mL + l * 30, 30, w * 2, 1.0f);
    dlayer4<30, 30, 4>(wa1, nullptr, HB + l * ST, gH + l * 60, 60, w * 4, 1.0f);
    dlayer4<30, 30, 4>(wa1, nullptr, LB + l * ST, gL + l * 60, 60, w * 4, 1.0f);
    if (tid < 64) {
        float sH = 0.f, sL = 0.f;
#pragma unroll
        for (int d = 0; d < 60; ++d) {
            sH = fmaf(HA[tid * ST + d], ba1[d], sH);
            sL = fmaf(LA[tid * ST + d], ba1[d], sL);
        }
        b2H[tid] = sH; b2L[tid] = sL;
    }
}

// ---------------- Kernel B: per-item chain (64 items/block, 16 waves, fused layers) ----------------
__global__ __launch_bounds__(1024) void chain_kernel(
    const float* __restrict__ spH, const float* __restrict__ spL,
    const float* __restrict__ w12H, const float* __restrict__ b12H,
    const float* __restrict__ w12L, const float* __restrict__ b12L,
    const float* __restrict__ mH, const float* __restrict__ b2H,
    const float* __restrict__ mL, const float* __restrict__ b2L,
    const float* __restrict__ gH, const float* __restrict__ gL,
    const float* __restrict__ ba1,
    const float* __restrict__ wf, const float* __restrict__ bf,
    const int* __restrict__ mI,
    float* __restrict__ out, float* __restrict__ aH, float* __restrict__ aL)
{
    __shared__ __align__(16) float HA[64 * ST];
    __shared__ __align__(16) float HB[64 * ST];
    __shared__ __align__(16) float LA[64 * ST];
    __shared__ __align__(16) float LB[64 * ST];
    __shared__ float PH[16 * 64], PL[16 * 64];

    const int tid = threadIdx.x;
    const int w = __builtin_amdgcn_readfirstlane(tid >> 6);
    const int l = tid & 63;
    const int b0 = blockIdx.x * 64;
    const int b = b0 + l;
    const float mf = (float)(*mI);
    const float xl = spL[b];

    {
        int r = tid >> 4, q = tid & 15;
        *(float4*)(HA + r * ST + 4 * q) = ((const float4*)(spH + (size_t)b0 * 64))[tid];
    }
    __syncthreads();

    // s12: H 63->30 (fused lin1) ; L 1->30 (fused lin2)
    dlayer4<63, 63, 2>(w12H, b12H, HA + l * ST, HB + l * ST, 30, w * 2, 1.0f);
#pragma unroll
    for (int k = 0; k < 2; ++k) {
        int o = w * 2 + k;
        if (o < 30) LA[l * ST + o] = fmaf(w12L[o], xl, b12L[o]);
    }
    __syncthreads();
    // data copies + s34: S = M @ data + bias2 (30->64)
    for (int i = tid; i < 1920; i += 1024) {
        int r = i / 30, c = i - r * 30;
        out[(size_t)b0 * 30 + i] = HB[r * ST + c];
        out[OFF1 + (size_t)b0 * 30 + i] = LA[r * ST + c];
    }
    dlayer4<30, 30, 4>(mH, b2H, HB + l * ST, HA + l * ST, 64, w * 4, 1.0f);
    dlayer4<30, 30, 4>(mL, b2L, LA + l * ST, LB + l * ST, 64, w * 4, 1.0f);
    __syncthreads();
    // softmax exp
    softmax_exp4(HA + l * ST, HB + l * ST, PH, w, l);
    softmax_exp4(LB + l * ST, LA + l * ST, PL, w, l);
    __syncthreads();
    // A-matrix writes (only consumed when m != 1)
    if (mf != 1.0f) {
        for (int i = tid; i < 4096; i += 1024) {
            int r = i >> 6, j = i & 63;
            aH[(size_t)b0 * 64 + i] = HB[r * ST + j] * inv16(PH, r);
            aL[(size_t)b0 * 64 + i] = LA[r * ST + j] * inv16(PL, r);
        }
    }
    // fused PV+feat: A60 = inv*(P @ G) + ba1  (64->60)
    {
        const float invH = inv16(PH, l);
        const float invL = inv16(PL, l);
        dlayerT4b<64, 60, 4>(gH, ba1, HB + l * ST, HA + l * ST, 60, w * 4, invH);
        dlayerT4b<64, 60, 4>(gL, ba1, LA + l * ST, LB + l * ST, 60, w * 4, invL);
    }
    __syncthreads();
    // A60 copies + fused output head: out7 = Wf @ [A60l ; A60h] + bf
    for (int i = tid; i < 3840; i += 1024) {
        int r = i / 60, c = i - r * 60;
        out[OFF2 + (size_t)b0 * 60 + i] = HA[r * ST + c];
        out[OFF4 + (size_t)b0 * 60 + i] = LB[r * ST + c];
    }
    if (w < 7) {
        float a = bf[w];
        const float* Wr = wf + w * 120;
#pragma unroll
        for (int c0 = 0; c0 < 60; c0 += 16) {
            const int CH = (60 - c0) < 16 ? (60 - c0) : 16;
            float x[16];
            if (CH == 16) load_chunk<16>(LB + l * ST + c0, x);
            else load_chunk<12>(LB + l * ST + c0, x);
#pragma unroll
            for (int j = 0; j < 16; ++j) if (j < CH) a = fmaf(Wr[c0 + j], x[j], a);
        }
#pragma unroll
        for (int c0 = 0; c0 < 60; c0 += 16) {
            const int CH = (60 - c0) < 16 ? (60 - c0) : 16;
            float x[16];
            if (CH == 16) load_chunk<16>(HA + l * ST + c0, x);
            else load_chunk<12>(HA + l * ST + c0, x);
#pragma unroll
            for (int j = 0; j < 16; ++j) if (j < CH) a = fmaf(Wr[60 + c0 + j], x[j], a);
        }
        out[OFF6 + (size_t)b * 7 + w] = a;
    }
}

// ---------------- Kernel D: momentum update (early-exit when m == 1) ----------------
// Dn already holds m*Dp (dict_chain); add (1-m) * data^T @ A via atomics.
__global__ __launch_bounds__(256) void momentum_kernel(
    const float* __restrict__ dataH, const float* __restrict__ dataL,
    const float* __restrict__ aH, const float* __restrict__ aL,
    const int* __restrict__ mI, float* __restrict__ out)
{
    const float mf = (float)(*mI);
    if (mf == 1.0f) return;
    const int tid = threadIdx.x;
    const int chunk = blockIdx.x & 63;
    const int mod = blockIdx.x >> 6;
    const float* data = mod ? dataL : dataH;
    const float* A = mod ? aL : aH;
    float* D = out + (mod ? OFF5 : OFF3);
    const int b0 = chunk * 256;
    const int j = tid & 63;
    const int g = tid >> 6;
    float acc[8];
#pragma unroll
    for (int k = 0; k < 8; ++k) acc[k] = 0.f;
    for (int bb = 0; bb < 256; ++bb) {
        float a = A[(size_t)(b0 + bb) * 64 + j];
#pragma unroll
        for (int k = 0; k < 8; ++k) {
            int c = g + 4 * k; c = c < 30 ? c : 29;
            acc[k] = fmaf(data[(size_t)(b0 + bb) * 30 + c], a, acc[k]);
        }
    }
    const float s = 1.0f - mf;
#pragma unroll
    for (int k = 0; k < 8; ++k) {
        int c = g + 4 * k;
        if (c < 30) atomicAdd(&D[c * 64 + j], s * acc[k]);
    }
}

extern "C" void kernel_launch(void* const* d_in, const int* in_sizes, int n_in,
                              void* d_out, int out_size, void* d_ws, size_t ws_size,
                              hipStream_t stream) {
    const float* H_HSI        = (const float*)d_in[0];
    const float* H_LiDAR      = (const float*)d_in[1];
    const float* HSI_D        = (const float*)d_in[2];
    const float* LiDAR_D      = (const float*)d_in[3];
    const float* Patch_HSI    = (const float*)d_in[4];
    const float* Patch_LiDAR  = (const float*)d_in[5];
    const float* D_Patch_HSI  = (const float*)d_in[6];
    const float* D_Patch_LiDAR= (const float*)d_in[7];
    const int*   mI           = (const int*)d_in[9];
    const float* w1_1 = (const float*)d_in[12];
    const float* b1_1 = (const float*)d_in[13];
    const float* w1_2 = (const float*)d_in[14];
    const float* b1_2 = (const float*)d_in[15];
    const float* w2_1 = (const float*)d_in[16];
    const float* b2_1 = (const float*)d_in[17];
    const float* w2_2 = (const float*)d_in[18];
    const float* b2_2 = (const float*)d_in[19];
    const float* wa1  = (const float*)d_in[20];
    const float* ba1  = (const float*)d_in[21];
    const float* wa2  = (const float*)d_in[22];
    const float* ba2  = (const float*)d_in[23];
    const float* wo1  = (const float*)d_in[24];
    const float* bo1  = (const float*)d_in[25];
    const float* wo2  = (const float*)d_in[26];
    const float* bo2  = (const float*)d_in[27];

    float* out = (float*)d_out;
    float* ws  = (float*)d_ws;

    patch_attend_kernel<<<NB / 4 + DN / 4 + 2, 256, 0, stream>>>(
        Patch_HSI, H_HSI, Patch_LiDAR, H_LiDAR, ws + SPH_OFF, ws + SPL_OFF,
        D_Patch_HSI, HSI_D, D_Patch_LiDAR, LiDAR_D, ws + DSPH_OFF, ws + DSPL_OFF,
        w1_1, b1_1, w1_2, b1_2, w2_1, b2_1, w2_2, b2_2, wo1, bo1, wo2, bo2,
        ws + W12H_OFF, ws + B12H_OFF, ws + W12L_OFF, ws + B12L_OFF,
        ws + WF_OFF, ws + BF_OFF);
    dict_chain_kernel<<<1, 1024, 0, stream>>>(
        ws + DSPH_OFF, ws + DSPL_OFF,
        ws + W12H_OFF, ws + B12H_OFF, ws + W12L_OFF, ws + B12L_OFF,
        wa1, ba1, wa2, ba2,
        ws + MH_OFF, ws + B2H_OFF, ws + ML_OFF, ws + B2L_OFF,
        ws + GH_OFF, ws + GL_OFF, mI, out);
    chain_kernel<<<NB / 64, 1024, 0, stream>>>(
        ws + SPH_OFF, ws + SPL_OFF,
        ws + W12H_OFF, ws + B12H_OFF, ws + W12L_OFF, ws + B12L_OFF,
        ws + MH_OFF, ws + B2H_OFF, ws + ML_OFF, ws + B2L_OFF,
        ws + GH_OFF, ws + GL_OFF, ba1, ws + WF_OFF, ws + BF_OFF,
        mI, out, ws + AH_OFF, ws + AL_OFF);
    momentum_kernel<<<128, 256, 0, stream>>>(
        out, out + OFF1, ws + AH_OFF, ws + AL_OFF, mI, out);
}

// Round 14
// 84.760 us; speedup vs baseline: 1.2816x; 1.1922x over previous
//
#include <hip/hip_runtime.h>
#include <math.h>

// ---------------- constants ----------------
#define NB 16384
#define DN 64
#define ST 68            // LDS row stride (16B-aligned rows)
// output offsets (floats)
#define OFF1 491520      // data_LiDAR
#define OFF2 983040      // HSI_A
#define OFF3 1966080     // HSI_Dn
#define OFF4 1968000     // LiDAR_A
#define OFF5 2951040     // LiDAR_Dn
#define OFF6 2952960     // output
// ws offsets (floats) — SPH/DSPH rows padded to stride 64
#define SPH_OFF  0
#define SPL_OFF  1048576
#define DSPH_OFF 1064960
#define DSPL_OFF 1069056
#define DPTH_OFF 1069120
#define DPTL_OFF 1071040
#define D2H_OFF  1072960
#define D2L_OFF  1076800
#define AH_OFF   1080640
#define AL_OFF   2129216

typedef const __attribute__((address_space(1))) void* gas_ptr;
typedef __attribute__((address_space(3))) void* las_ptr;

__device__ __forceinline__ float wredmax(float v) {
#pragma unroll
    for (int m = 32; m; m >>= 1) v = fmaxf(v, __shfl_xor(v, m, 64));
    return v;
}
__device__ __forceinline__ float wredsum(float v) {
#pragma unroll
    for (int m = 32; m; m >>= 1) v += __shfl_xor(v, m, 64);
    return v;
}

// ---- f4-vectorized chunk loader: xrow 16B-aligned.
template<int CH>
__device__ __forceinline__ void load_chunk(const float* __restrict__ xrow, float* __restrict__ x) {
    const int NQ = CH >> 2;
#pragma unroll
    for (int q = 0; q < NQ; ++q) {
        float4 v = *(const float4*)(xrow + 4 * q);
        x[4 * q] = v.x; x[4 * q + 1] = v.y; x[4 * q + 2] = v.z; x[4 * q + 3] = v.w;
    }
#pragma unroll
    for (int j = NQ * 4; j < CH; ++j) x[j] = xrow[j];
}

// y[o] = scale*(bias[o] + sum_c W[o*RS+c]*x[c]) for o in [o0,o0+PER) ∩ [0,OUTS)
template<int INS, int RS, int PER>
__device__ __forceinline__ void dlayer4(const float* __restrict__ W,
                                        const float* __restrict__ bias,
                                        const float* __restrict__ xb,
                                        float* __restrict__ yb,
                                        const int OUTS, const int o0,
                                        const float scale)
{
    float acc[PER];
#pragma unroll
    for (int k = 0; k < PER; ++k) {
        int oc = o0 + k; oc = oc < OUTS ? oc : OUTS - 1;
        acc[k] = bias ? bias[oc] : 0.0f;
    }
#pragma unroll
    for (int c0 = 0; c0 < INS; c0 += 16) {
        const int CHv = (INS - c0) < 16 ? (INS - c0) : 16;
        float x[16];
        if (CHv == 16) load_chunk<16>(xb + c0, x);
        else if (CHv == 15) load_chunk<15>(xb + c0, x);
        else if (CHv == 14) load_chunk<14>(xb + c0, x);
        else if (CHv == 13) load_chunk<13>(xb + c0, x);
        else if (CHv == 12) load_chunk<12>(xb + c0, x);
        else {
#pragma unroll
            for (int j = 0; j < 16; ++j) if (j < CHv) x[j] = xb[c0 + j];
        }
#pragma unroll
        for (int k = 0; k < PER; ++k) {
            int oc = o0 + k; oc = oc < OUTS ? oc : OUTS - 1;
            const float* Wr = W + oc * RS + c0;
            float a = acc[k];
#pragma unroll
            for (int j = 0; j < 16; ++j) if (j < CHv) a = fmaf(Wr[j], x[j], a);
            acc[k] = a;
        }
    }
#pragma unroll
    for (int k = 0; k < PER; ++k) {
        int o = o0 + k;
        if (o < OUTS) yb[o] = acc[k] * scale;
    }
}

// y[o] = scale * sum_c W[c*CS+o]*x[c]  (transposed weights; INS mult of 16)
template<int INS, int CS, int PER>
__device__ __forceinline__ void dlayerT4(const float* __restrict__ W,
                                         const float* __restrict__ xb,
                                         float* __restrict__ yb,
                                         const int OUTS, const int o0,
                                         const float scale)
{
    float acc[PER];
#pragma unroll
    for (int k = 0; k < PER; ++k) acc[k] = 0.0f;
#pragma unroll
    for (int c0 = 0; c0 < INS; c0 += 16) {
        float x[16];
        load_chunk<16>(xb + c0, x);
#pragma unroll
        for (int j = 0; j < 16; ++j) {
            const float* Wr = W + (c0 + j) * CS + o0;
#pragma unroll
            for (int k = 0; k < PER; ++k) acc[k] = fmaf(Wr[k], x[j], acc[k]);
        }
    }
#pragma unroll
    for (int k = 0; k < PER; ++k) {
        int o = o0 + k;
        if (o < OUTS) yb[o] = acc[k] * scale;
    }
}

// exp(S - max(S)) over a 64-wide row (f4); wave w covers cols 4w..4w+3 (16 waves).
__device__ __forceinline__ void softmax_exp4(const float* __restrict__ Sb,
                                             float* __restrict__ Qb,
                                             float* __restrict__ P,
                                             const int w, const int l)
{
    const float4* S4 = (const float4*)Sb;
    float4 m4 = S4[0];
#pragma unroll
    for (int q = 1; q < 16; ++q) {
        float4 v = S4[q];
        m4.x = fmaxf(m4.x, v.x); m4.y = fmaxf(m4.y, v.y);
        m4.z = fmaxf(m4.z, v.z); m4.w = fmaxf(m4.w, v.w);
    }
    const float mx = fmaxf(fmaxf(m4.x, m4.y), fmaxf(m4.z, m4.w));
    float4 sv = S4[w];
    float4 e;
    e.x = __expf(sv.x - mx); e.y = __expf(sv.y - mx);
    e.z = __expf(sv.z - mx); e.w = __expf(sv.w - mx);
    ((float4*)Qb)[w] = e;
    P[w * 64 + l] = (e.x + e.y) + (e.z + e.w);
}

// 1/sum over 16 per-wave partials
__device__ __forceinline__ float inv16(const float* __restrict__ P, const int l)
{
    float s0 = P[l], s1 = P[64 + l], s2 = P[128 + l], s3 = P[192 + l];
#pragma unroll
    for (int g = 4; g < 16; g += 4) {
        s0 += P[g * 64 + l];
        s1 += P[(g + 1) * 64 + l];
        s2 += P[(g + 2) * 64 + l];
        s3 += P[(g + 3) * 64 + l];
    }
    return 1.0f / ((s0 + s1) + (s2 + s3));
}

// ---------------- Kernel A: patch attention (4 items/block; dict grid merged) ----------------
__global__ __launch_bounds__(256) void patch_attend_kernel(
    const float* __restrict__ patchH, const float* __restrict__ xH,
    const float* __restrict__ patchL, const float* __restrict__ xL,
    float* __restrict__ spH, float* __restrict__ spL,
    const float* __restrict__ dpH, const float* __restrict__ dxH,
    const float* __restrict__ dpL, const float* __restrict__ dxL,
    float* __restrict__ dspH, float* __restrict__ dspL)
{
    __shared__ __align__(16) float ph[4 * 3087];
    __shared__ __align__(16) float pl_[4 * 49];
    __shared__ __align__(16) float xh[4 * 63];
    __shared__ float xls[4];
    __shared__ float pw[4 * 49];

    const int tid = threadIdx.x;
    const bool isD = blockIdx.x >= (NB / 4);
    const int b0 = (isD ? (blockIdx.x - NB / 4) : blockIdx.x) * 4;
    const float* PH = isD ? dpH : patchH;
    const float* XH = isD ? dxH : xH;
    const float* PL = isD ? dpL : patchL;
    const float* XL = isD ? dxL : xL;
    float* SH = isD ? dspH : spH;
    float* SL = isD ? dspL : spL;
    {
        const float4* s4 = (const float4*)(PH + (size_t)b0 * 3087);
        float4* d4 = (float4*)ph;
        for (int i = tid; i < 3087; i += 256) {
            __builtin_amdgcn_global_load_lds((gas_ptr)(const void*)(s4 + i),
                                             (las_ptr)(void*)(d4 + i), 16, 0, 0);
        }
        if (tid < 49) ((float4*)pl_)[tid] = ((const float4*)(PL + (size_t)b0 * 49))[tid];
        if (tid >= 64 && tid < 127) ((float4*)xh)[tid - 64] = ((const float4*)(XH + (size_t)b0 * 63))[tid - 64];
        if (tid == 255) *((float4*)xls) = *((const float4*)(XL + b0));
    }
    asm volatile("s_waitcnt vmcnt(0)" ::: "memory");
    __syncthreads();

    const int w = tid >> 6, l = tid & 63;
    const float* phw = ph + w * 3087;
    const float* plw = pl_ + w * 49;
    const float* xhw = xh + w * 63;
    const float xlw = xls[w];

    float eh = -INFINITY, el = -INFINITY;
    if (l < 49) {
        float acc = 0.f;
#pragma unroll
        for (int c = 0; c < 63; ++c) {
            float t = xhw[c] - phw[c * 49 + l] + 1e-6f;
            acc = fmaf(t, t, acc);
        }
        eh = __expf(-sqrtf(acc));
        float tl = xlw - plw[l] + 1e-6f;
        el = __expf(-fabsf(tl));
    }
    float mh = wredmax(eh), ml = wredmax(el);
    float qh = (l < 49) ? __expf(eh - mh) : 0.f;
    float ql = (l < 49) ? __expf(el - ml) : 0.f;
    float sh = wredsum(qh);
    float sl = wredsum(ql);
    if (l < 49) pw[w * 49 + l] = qh / sh;
    float spl_v = wredsum((l < 49) ? plw[l] * (ql / sl) : 0.f);
    if (l == 0) SL[b0 + w] = spl_v;
    __syncthreads();
    if (l < 63) {
        float acc = 0.f;
        const float* pww = pw + w * 49;
#pragma unroll
        for (int s = 0; s < 49; ++s) acc = fmaf(phw[l * 49 + s], pww[s], acc);
        SH[(size_t)(b0 + w) * 64 + l] = acc;   // stride-64 rows (col 63 unused)
    }
}

// ---------------- Kernel C: dictionary chain (1 block, 16 waves, H+L interleaved) ----------------
__global__ __launch_bounds__(1024) void dict_chain_kernel(
    const float* __restrict__ dsph, const float* __restrict__ dspl,
    const float* __restrict__ w1_1, const float* __restrict__ b1_1,
    const float* __restrict__ w1_2, const float* __restrict__ b1_2,
    const float* __restrict__ w2_1, const float* __restrict__ b2_1,
    const float* __restrict__ w2_2, const float* __restrict__ b2_2,
    const float* __restrict__ wa2, const float* __restrict__ ba2,
    float* __restrict__ dptH, float* __restrict__ dptL,
    float* __restrict__ d2H, float* __restrict__ d2L,
    const int* __restrict__ mI, float* __restrict__ out)
{
    __shared__ __align__(16) float HA[64 * ST];
    __shared__ __align__(16) float HB[64 * ST];
    __shared__ __align__(16) float LA[64 * ST];
    __shared__ __align__(16) float LB[64 * ST];
    __shared__ float XLs[64];
    const int tid = threadIdx.x;
    const int w = __builtin_amdgcn_readfirstlane(tid >> 6);
    const int l = tid & 63;
    const float mf = (float)(*mI);
    {
        int r = tid >> 4, q = tid & 15;
        *(float4*)(HA + r * ST + 4 * q) = ((const float4*)dsph)[tid];
        if (tid < 64) XLs[tid] = dspl[tid];
    }
    __syncthreads();
    // s1: H 63->45 ; L 1->15
    dlayer4<63, 63, 3>(w1_1, b1_1, HA + l * ST, HB + l * ST, 45, w * 3, 1.0f);
    dlayer4<1, 1, 1>(w2_1, b2_1, XLs + l, LA + l * ST, 15, w, 1.0f);
    __syncthreads();
    // s2: H 45->30 ; L 15->30
    dlayer4<45, 45, 2>(w1_2, b1_2, HB + l * ST, HA + l * ST, 30, w * 2, 1.0f);
    dlayer4<15, 15, 2>(w2_2, b2_2, LA + l * ST, LB + l * ST, 30, w * 2, 1.0f);
    __syncthreads();
    // dpt copies + Dn = m*Dp + s3 (wa2 30->60)
    for (int i = tid; i < 1920; i += 1024) {
        int r = i / 30, c = i - r * 30;
        dptH[i] = HA[r * ST + c];
        dptL[i] = LB[r * ST + c];
    }
    for (int i = tid; i < 1920; i += 1024) {
        int c = i >> 6, j = i & 63;
        out[OFF3 + i] = mf * HA[j * ST + c];
        out[OFF5 + i] = mf * LB[j * ST + c];
    }
    dlayer4<30, 30, 4>(wa2, ba2, HA + l * ST, HB + l * ST, 60, w * 4, 1.0f);
    dlayer4<30, 30, 4>(wa2, ba2, LB + l * ST, LA + l * ST, 60, w * 4, 1.0f);
    __syncthreads();
    for (int i = tid; i < 3840; i += 1024) {
        int r = i / 60, c = i - r * 60;
        d2H[i] = HB[r * ST + c];
        d2L[i] = LA[r * ST + c];
    }
}

// ---------------- Kernel B: per-item chain (64 items/block, 16 waves, interleaved H+L) ----------------
__global__ __launch_bounds__(1024) void chain_kernel(
    const float* __restrict__ spH, const float* __restrict__ spL,
    const float* __restrict__ dptH, const float* __restrict__ dptL,
    const float* __restrict__ d2H, const float* __restrict__ d2L,
    const float* __restrict__ w1_1, const float* __restrict__ b1_1,
    const float* __restrict__ w1_2, const float* __restrict__ b1_2,
    const float* __restrict__ w2_1, const float* __restrict__ b2_1,
    const float* __restrict__ w2_2, const float* __restrict__ b2_2,
    const float* __restrict__ wa1, const float* __restrict__ ba1,
    const float* __restrict__ wo1, const float* __restrict__ bo1,
    const float* __restrict__ wo2, const float* __restrict__ bo2,
    const int* __restrict__ mI,
    float* __restrict__ out, float* __restrict__ aH, float* __restrict__ aL)
{
    __shared__ __align__(16) float HA[64 * ST];
    __shared__ __align__(16) float HB[64 * ST];
    __shared__ __align__(16) float LA[64 * ST];
    __shared__ __align__(16) float LB[64 * ST];
    __shared__ float XLs[64];
    __shared__ float PH[16 * 64], PL[16 * 64];

    const int tid = threadIdx.x;
    const int w = __builtin_amdgcn_readfirstlane(tid >> 6);
    const int l = tid & 63;
    const int b0 = blockIdx.x * 64;
    const int b = b0 + l;
    const float mf = (float)(*mI);

    {
        int r = tid >> 4, q = tid & 15;
        *(float4*)(HA + r * ST + 4 * q) = ((const float4*)(spH + (size_t)b0 * 64))[tid];
        if (tid < 64) XLs[tid] = spL[b0 + tid];
    }
    __syncthreads();

    // s1: H 63->45 ; L 1->15
    dlayer4<63, 63, 3>(w1_1, b1_1, HA + l * ST, HB + l * ST, 45, w * 3, 1.0f);
    dlayer4<1, 1, 1>(w2_1, b2_1, XLs + l, LA + l * ST, 15, w, 1.0f);
    __syncthreads();
    // s2: H 45->30 ; L 15->30
    dlayer4<45, 45, 2>(w1_2, b1_2, HB + l * ST, HA + l * ST, 30, w * 2, 1.0f);
    dlayer4<15, 15, 2>(w2_2, b2_2, LA + l * ST, LB + l * ST, 30, w * 2, 1.0f);
    __syncthreads();
    // data copies + s3: 30->60 (wa1) both branches
    for (int i = tid; i < 1920; i += 1024) {
        int r = i / 30, c = i - r * 30;
        out[(size_t)b0 * 30 + i] = HA[r * ST + c];
        out[OFF1 + (size_t)b0 * 30 + i] = LB[r * ST + c];
    }
    dlayer4<30, 30, 4>(wa1, ba1, HA + l * ST, HB + l * ST, 60, w * 4, 1.0f);
    dlayer4<30, 30, 4>(wa1, ba1, LB + l * ST, LA + l * ST, 60, w * 4, 1.0f);
    __syncthreads();
    // s4: S = H1 @ D2^T (60->64) both branches
    dlayer4<60, 60, 4>(d2H, nullptr, HB + l * ST, HA + l * ST, 64, w * 4, 1.0f);
    dlayer4<60, 60, 4>(d2L, nullptr, LA + l * ST, LB + l * ST, 64, w * 4, 1.0f);
    __syncthreads();
    // s5: exp(S - max) both branches
    softmax_exp4(HA + l * ST, HB + l * ST, PH, w, l);
    softmax_exp4(LB + l * ST, LA + l * ST, PL, w, l);
    __syncthreads();
    // A-matrix writes (only consumed when m != 1)
    if (mf != 1.0f) {
        for (int i = tid; i < 4096; i += 1024) {
            int r = i >> 6, j = i & 63;
            aH[(size_t)b0 * 64 + i] = HB[r * ST + j] * inv16(PH, r);
            aL[(size_t)b0 * 64 + i] = LA[r * ST + j] * inv16(PL, r);
        }
    }
    {
        const float invH = inv16(PH, l);
        const float invL = inv16(PL, l);
        dlayerT4<64, 30, 2>(dptH, HB + l * ST, HA + l * ST, 30, w * 2, invH);
        dlayerT4<64, 30, 2>(dptL, LA + l * ST, LB + l * ST, 30, w * 2, invL);
    }
    __syncthreads();
    // s8: 30->60 (wa1) both branches
    dlayer4<30, 30, 4>(wa1, ba1, HA + l * ST, HB + l * ST, 60, w * 4, 1.0f);
    dlayer4<30, 30, 4>(wa1, ba1, LB + l * ST, LA + l * ST, 60, w * 4, 1.0f);
    __syncthreads();
    // HSI_A / LiDAR_A copies
    for (int i = tid; i < 3840; i += 1024) {
        int r = i / 60, c = i - r * 60;
        out[OFF2 + (size_t)b0 * 60 + i] = HB[r * ST + c];
        out[OFF4 + (size_t)b0 * 60 + i] = LA[r * ST + c];
    }
    // o1: 120->60 = wo1[:, :60]@A60l + wo1[:, 60:]@A60h (f4 chunked)
    {
        const int o0 = w * 4;
        float acc[4];
#pragma unroll
        for (int k = 0; k < 4; ++k) acc[k] = (o0 + k < 60) ? bo1[o0 + k] : 0.0f;
#pragma unroll
        for (int c0 = 0; c0 < 60; c0 += 16) {
            const int CH = (60 - c0) < 16 ? (60 - c0) : 16;
            float x[16];
            if (CH == 16) load_chunk<16>(LA + l * ST + c0, x);
            else load_chunk<12>(LA + l * ST + c0, x);
#pragma unroll
            for (int k = 0; k < 4; ++k) {
                int oc = o0 + k; oc = oc < 60 ? oc : 59;
                const float* Wr = wo1 + oc * 120 + c0;
                float a = acc[k];
#pragma unroll
                for (int j = 0; j < 16; ++j) if (j < CH) a = fmaf(Wr[j], x[j], a);
                acc[k] = a;
            }
        }
#pragma unroll
        for (int c0 = 0; c0 < 60; c0 += 16) {
            const int CH = (60 - c0) < 16 ? (60 - c0) : 16;
            float x[16];
            if (CH == 16) load_chunk<16>(HB + l * ST + c0, x);
            else load_chunk<12>(HB + l * ST + c0, x);
#pragma unroll
            for (int k = 0; k < 4; ++k) {
                int oc = o0 + k; oc = oc < 60 ? oc : 59;
                const float* Wr = wo1 + oc * 120 + 60 + c0;
                float a = acc[k];
#pragma unroll
                for (int j = 0; j < 16; ++j) if (j < CH) a = fmaf(Wr[j], x[j], a);
                acc[k] = a;
            }
        }
        if (o0 < 60) {
            float4 av; av.x = acc[0]; av.y = acc[1]; av.z = acc[2]; av.w = acc[3];
            *((float4*)(HA + l * ST + o0)) = av;
        }
    }
    __syncthreads();
    // o2: 60->7 (waves 0-6)
    if (w < 7) {
        float a = bo2[w];
        const float* Wr = wo2 + w * 60;
#pragma unroll
        for (int c0 = 0; c0 < 60; c0 += 16) {
            const int CH = (60 - c0) < 16 ? (60 - c0) : 16;
            float x[16];
            if (CH == 16) load_chunk<16>(HA + l * ST + c0, x);
            else load_chunk<12>(HA + l * ST + c0, x);
#pragma unroll
            for (int j = 0; j < 16; ++j) if (j < CH) a = fmaf(Wr[c0 + j], x[j], a);
        }
        out[OFF6 + (size_t)b * 7 + w] = a;
    }
}

// ---------------- Kernel D: momentum update (early-exit when m == 1) ----------------
// Dn already holds m*Dp (dict_chain); add (1-m) * data^T @ A via atomics.
__global__ __launch_bounds__(256) void momentum_kernel(
    const float* __restrict__ dataH, const float* __restrict__ dataL,
    const float* __restrict__ aH, const float* __restrict__ aL,
    const int* __restrict__ mI, float* __restrict__ out)
{
    const float mf = (float)(*mI);
    if (mf == 1.0f) return;
    const int tid = threadIdx.x;
    const int chunk = blockIdx.x & 63;
    const int mod = blockIdx.x >> 6;
    const float* data = mod ? dataL : dataH;
    const float* A = mod ? aL : aH;
    float* D = out + (mod ? OFF5 : OFF3);
    const int b0 = chunk * 256;
    const int j = tid & 63;
    const int g = tid >> 6;
    float acc[8];
#pragma unroll
    for (int k = 0; k < 8; ++k) acc[k] = 0.f;
    for (int bb = 0; bb < 256; ++bb) {
        float a = A[(size_t)(b0 + bb) * 64 + j];
#pragma unroll
        for (int k = 0; k < 8; ++k) {
            int c = g + 4 * k; c = c < 30 ? c : 29;
            acc[k] = fmaf(data[(size_t)(b0 + bb) * 30 + c], a, acc[k]);
        }
    }
    const float s = 1.0f - mf;
#pragma unroll
    for (int k = 0; k < 8; ++k) {
        int c = g + 4 * k;
        if (c < 30) atomicAdd(&D[c * 64 + j], s * acc[k]);
    }
}

extern "C" void kernel_launch(void* const* d_in, const int* in_sizes, int n_in,
                              void* d_out, int out_size, void* d_ws, size_t ws_size,
                              hipStream_t stream) {
    const float* H_HSI        = (const float*)d_in[0];
    const float* H_LiDAR      = (const float*)d_in[1];
    const float* HSI_D        = (const float*)d_in[2];
    const float* LiDAR_D      = (const float*)d_in[3];
    const float* Patch_HSI    = (const float*)d_in[4];
    const float* Patch_LiDAR  = (const float*)d_in[5];
    const float* D_Patch_HSI  = (const float*)d_in[6];
    const float* D_Patch_LiDAR= (const float*)d_in[7];
    const int*   mI           = (const int*)d_in[9];
    const float* w1_1 = (const float*)d_in[12];
    const float* b1_1 = (const float*)d_in[13];
    const float* w1_2 = (const float*)d_in[14];
    const float* b1_2 = (const float*)d_in[15];
    const float* w2_1 = (const float*)d_in[16];
    const float* b2_1 = (const float*)d_in[17];
    const float* w2_2 = (const float*)d_in[18];
    const float* b2_2 = (const float*)d_in[19];
    const float* wa1  = (const float*)d_in[20];
    const float* ba1  = (const float*)d_in[21];
    const float* wa2  = (const float*)d_in[22];
    const float* ba2  = (const float*)d_in[23];
    const float* wo1  = (const float*)d_in[24];
    const float* bo1  = (const float*)d_in[25];
    const float* wo2  = (const float*)d_in[26];
    const float* bo2  = (const float*)d_in[27];

    float* out = (float*)d_out;
    float* ws  = (float*)d_ws;

    patch_attend_kernel<<<NB / 4 + DN / 4, 256, 0, stream>>>(
        Patch_HSI, H_HSI, Patch_LiDAR, H_LiDAR, ws + SPH_OFF, ws + SPL_OFF,
        D_Patch_HSI, HSI_D, D_Patch_LiDAR, LiDAR_D, ws + DSPH_OFF, ws + DSPL_OFF);
    dict_chain_kernel<<<1, 1024, 0, stream>>>(
        ws + DSPH_OFF, ws + DSPL_OFF,
        w1_1, b1_1, w1_2, b1_2, w2_1, b2_1, w2_2, b2_2, wa2, ba2,
        ws + DPTH_OFF, ws + DPTL_OFF, ws + D2H_OFF, ws + D2L_OFF, mI, out);
    chain_kernel<<<NB / 64, 1024, 0, stream>>>(
        ws + SPH_OFF, ws + SPL_OFF,
        ws + DPTH_OFF, ws + DPTL_OFF, ws + D2H_OFF, ws + D2L_OFF,
        w1_1, b1_1, w1_2, b1_2, w2_1, b2_1, w2_2, b2_2,
        wa1, ba1, wo1, bo1, wo2, bo2, mI,
        out, ws + AH_OFF, ws + AL_OFF);
    momentum_kernel<<<128, 256, 0, stream>>>(
        out, out + OFF1, ws + AH_OFF, ws + AL_OFF, mI, out);
}

// Round 15
// 83.291 us; speedup vs baseline: 1.3042x; 1.0176x over previous
//
#include <hip/hip_runtime.h>
#include <math.h>

// ---------------- constants ----------------
#define NB 16384
#define DN 64
#define ST 68            // LDS row stride (16B-aligned rows)
// output offsets (floats)
#define OFF1 491520      // data_LiDAR
#define OFF2 983040      // HSI_A
#define OFF3 1966080     // HSI_Dn
#define OFF4 1968000     // LiDAR_A
#define OFF5 2951040     // LiDAR_Dn
#define OFF6 2952960     // output
// ws offsets (floats) — SPH/DSPH rows padded to stride 64
#define SPH_OFF  0
#define SPL_OFF  1048576
#define DSPH_OFF 1064960
#define DSPL_OFF 1069056
#define DPTH_OFF 1069120
#define DPTL_OFF 1071040
#define D2H_OFF  1072960
#define D2L_OFF  1076800

typedef const __attribute__((address_space(1))) void* gas_ptr;
typedef __attribute__((address_space(3))) void* las_ptr;

__device__ __forceinline__ float wredmax(float v) {
#pragma unroll
    for (int m = 32; m; m >>= 1) v = fmaxf(v, __shfl_xor(v, m, 64));
    return v;
}
__device__ __forceinline__ float wredsum(float v) {
#pragma unroll
    for (int m = 32; m; m >>= 1) v += __shfl_xor(v, m, 64);
    return v;
}

// ---- f4-vectorized chunk loader: xrow 16B-aligned.
template<int CH>
__device__ __forceinline__ void load_chunk(const float* __restrict__ xrow, float* __restrict__ x) {
    const int NQ = CH >> 2;
#pragma unroll
    for (int q = 0; q < NQ; ++q) {
        float4 v = *(const float4*)(xrow + 4 * q);
        x[4 * q] = v.x; x[4 * q + 1] = v.y; x[4 * q + 2] = v.z; x[4 * q + 3] = v.w;
    }
#pragma unroll
    for (int j = NQ * 4; j < CH; ++j) x[j] = xrow[j];
}

// y[o] = scale*(bias[o] + sum_c W[o*RS+c]*x[c]) for o in [o0,o0+PER) ∩ [0,OUTS)
template<int INS, int RS, int PER>
__device__ __forceinline__ void dlayer4(const float* __restrict__ W,
                                        const float* __restrict__ bias,
                                        const float* __restrict__ xb,
                                        float* __restrict__ yb,
                                        const int OUTS, const int o0,
                                        const float scale)
{
    float acc[PER];
#pragma unroll
    for (int k = 0; k < PER; ++k) {
        int oc = o0 + k; oc = oc < OUTS ? oc : OUTS - 1;
        acc[k] = bias ? bias[oc] : 0.0f;
    }
#pragma unroll
    for (int c0 = 0; c0 < INS; c0 += 16) {
        const int CHv = (INS - c0) < 16 ? (INS - c0) : 16;
        float x[16];
        if (CHv == 16) load_chunk<16>(xb + c0, x);
        else if (CHv == 15) load_chunk<15>(xb + c0, x);
        else if (CHv == 14) load_chunk<14>(xb + c0, x);
        else if (CHv == 13) load_chunk<13>(xb + c0, x);
        else if (CHv == 12) load_chunk<12>(xb + c0, x);
        else {
#pragma unroll
            for (int j = 0; j < 16; ++j) if (j < CHv) x[j] = xb[c0 + j];
        }
#pragma unroll
        for (int k = 0; k < PER; ++k) {
            int oc = o0 + k; oc = oc < OUTS ? oc : OUTS - 1;
            const float* Wr = W + oc * RS + c0;
            float a = acc[k];
#pragma unroll
            for (int j = 0; j < 16; ++j) if (j < CHv) a = fmaf(Wr[j], x[j], a);
            acc[k] = a;
        }
    }
#pragma unroll
    for (int k = 0; k < PER; ++k) {
        int o = o0 + k;
        if (o < OUTS) yb[o] = acc[k] * scale;
    }
}

// y[o] = scale * sum_c W[c*CS+o]*x[c]  (transposed weights; INS mult of 16)
template<int INS, int CS, int PER>
__device__ __forceinline__ void dlayerT4(const float* __restrict__ W,
                                         const float* __restrict__ xb,
                                         float* __restrict__ yb,
                                         const int OUTS, const int o0,
                                         const float scale)
{
    float acc[PER];
#pragma unroll
    for (int k = 0; k < PER; ++k) acc[k] = 0.0f;
#pragma unroll
    for (int c0 = 0; c0 < INS; c0 += 16) {
        float x[16];
        load_chunk<16>(xb + c0, x);
#pragma unroll
        for (int j = 0; j < 16; ++j) {
            const float* Wr = W + (c0 + j) * CS + o0;
#pragma unroll
            for (int k = 0; k < PER; ++k) acc[k] = fmaf(Wr[k], x[j], acc[k]);
        }
    }
#pragma unroll
    for (int k = 0; k < PER; ++k) {
        int o = o0 + k;
        if (o < OUTS) yb[o] = acc[k] * scale;
    }
}

// exp(S - max(S)) over a 64-wide row (f4); wave w covers cols 4w..4w+3 (16 waves).
__device__ __forceinline__ void softmax_exp4(const float* __restrict__ Sb,
                                             float* __restrict__ Qb,
                                             float* __restrict__ P,
                                             const int w, const int l)
{
    const float4* S4 = (const float4*)Sb;
    float4 m4 = S4[0];
#pragma unroll
    for (int q = 1; q < 16; ++q) {
        float4 v = S4[q];
        m4.x = fmaxf(m4.x, v.x); m4.y = fmaxf(m4.y, v.y);
        m4.z = fmaxf(m4.z, v.z); m4.w = fmaxf(m4.w, v.w);
    }
    const float mx = fmaxf(fmaxf(m4.x, m4.y), fmaxf(m4.z, m4.w));
    float4 sv = S4[w];
    float4 e;
    e.x = __expf(sv.x - mx); e.y = __expf(sv.y - mx);
    e.z = __expf(sv.z - mx); e.w = __expf(sv.w - mx);
    ((float4*)Qb)[w] = e;
    P[w * 64 + l] = (e.x + e.y) + (e.z + e.w);
}

// 1/sum over 16 per-wave partials
__device__ __forceinline__ float inv16(const float* __restrict__ P, const int l)
{
    float s0 = P[l], s1 = P[64 + l], s2 = P[128 + l], s3 = P[192 + l];
#pragma unroll
    for (int g = 4; g < 16; g += 4) {
        s0 += P[g * 64 + l];
        s1 += P[(g + 1) * 64 + l];
        s2 += P[(g + 2) * 64 + l];
        s3 += P[(g + 3) * 64 + l];
    }
    return 1.0f / ((s0 + s1) + (s2 + s3));
}

// ---------------- Kernel A: patch attention (4 items/block; dict grid merged) ----------------
__global__ __launch_bounds__(256) void patch_attend_kernel(
    const float* __restrict__ patchH, const float* __restrict__ xH,
    const float* __restrict__ patchL, const float* __restrict__ xL,
    float* __restrict__ spH, float* __restrict__ spL,
    const float* __restrict__ dpH, const float* __restrict__ dxH,
    const float* __restrict__ dpL, const float* __restrict__ dxL,
    float* __restrict__ dspH, float* __restrict__ dspL)
{
    __shared__ __align__(16) float ph[4 * 3087];
    __shared__ __align__(16) float pl_[4 * 49];
    __shared__ __align__(16) float xh[4 * 63];
    __shared__ float xls[4];
    __shared__ float pw[4 * 49];

    const int tid = threadIdx.x;
    const bool isD = blockIdx.x >= (NB / 4);
    const int b0 = (isD ? (blockIdx.x - NB / 4) : blockIdx.x) * 4;
    const float* PH = isD ? dpH : patchH;
    const float* XH = isD ? dxH : xH;
    const float* PL = isD ? dpL : patchL;
    const float* XL = isD ? dxL : xL;
    float* SH = isD ? dspH : spH;
    float* SL = isD ? dspL : spL;
    {
        const float4* s4 = (const float4*)(PH + (size_t)b0 * 3087);
        float4* d4 = (float4*)ph;
        for (int i = tid; i < 3087; i += 256) {
            __builtin_amdgcn_global_load_lds((gas_ptr)(const void*)(s4 + i),
                                             (las_ptr)(void*)(d4 + i), 16, 0, 0);
        }
        if (tid < 49) ((float4*)pl_)[tid] = ((const float4*)(PL + (size_t)b0 * 49))[tid];
        if (tid >= 64 && tid < 127) ((float4*)xh)[tid - 64] = ((const float4*)(XH + (size_t)b0 * 63))[tid - 64];
        if (tid == 255) *((float4*)xls) = *((const float4*)(XL + b0));
    }
    asm volatile("s_waitcnt vmcnt(0)" ::: "memory");
    __syncthreads();

    const int w = tid >> 6, l = tid & 63;
    const float* phw = ph + w * 3087;
    const float* plw = pl_ + w * 49;
    const float* xhw = xh + w * 63;
    const float xlw = xls[w];

    float eh = -INFINITY, el = -INFINITY;
    if (l < 49) {
        float acc = 0.f;
#pragma unroll
        for (int c = 0; c < 63; ++c) {
            float t = xhw[c] - phw[c * 49 + l] + 1e-6f;
            acc = fmaf(t, t, acc);
        }
        eh = __expf(-sqrtf(acc));
        float tl = xlw - plw[l] + 1e-6f;
        el = __expf(-fabsf(tl));
    }
    float mh = wredmax(eh), ml = wredmax(el);
    float qh = (l < 49) ? __expf(eh - mh) : 0.f;
    float ql = (l < 49) ? __expf(el - ml) : 0.f;
    float sh = wredsum(qh);
    float sl = wredsum(ql);
    if (l < 49) pw[w * 49 + l] = qh / sh;
    float spl_v = wredsum((l < 49) ? plw[l] * (ql / sl) : 0.f);
    if (l == 0) SL[b0 + w] = spl_v;
    __syncthreads();
    if (l < 63) {
        float acc = 0.f;
        const float* pww = pw + w * 49;
#pragma unroll
        for (int s = 0; s < 49; ++s) acc = fmaf(phw[l * 49 + s], pww[s], acc);
        SH[(size_t)(b0 + w) * 64 + l] = acc;   // stride-64 rows (col 63 unused)
    }
}

// ---------------- Kernel C: dictionary chain (1 block, 16 waves, H+L interleaved) ----------------
__global__ __launch_bounds__(1024) void dict_chain_kernel(
    const float* __restrict__ dsph, const float* __restrict__ dspl,
    const float* __restrict__ w1_1, const float* __restrict__ b1_1,
    const float* __restrict__ w1_2, const float* __restrict__ b1_2,
    const float* __restrict__ w2_1, const float* __restrict__ b2_1,
    const float* __restrict__ w2_2, const float* __restrict__ b2_2,
    const float* __restrict__ wa2, const float* __restrict__ ba2,
    float* __restrict__ dptH, float* __restrict__ dptL,
    float* __restrict__ d2H, float* __restrict__ d2L,
    const int* __restrict__ mI, float* __restrict__ out)
{
    __shared__ __align__(16) float HA[64 * ST];
    __shared__ __align__(16) float HB[64 * ST];
    __shared__ __align__(16) float LA[64 * ST];
    __shared__ __align__(16) float LB[64 * ST];
    __shared__ float XLs[64];
    const int tid = threadIdx.x;
    const int w = __builtin_amdgcn_readfirstlane(tid >> 6);
    const int l = tid & 63;
    const float mf = (float)(*mI);
    {
        int r = tid >> 4, q = tid & 15;
        *(float4*)(HA + r * ST + 4 * q) = ((const float4*)dsph)[tid];
        if (tid < 64) XLs[tid] = dspl[tid];
    }
    __syncthreads();
    // s1: H 63->45 ; L 1->15
    dlayer4<63, 63, 3>(w1_1, b1_1, HA + l * ST, HB + l * ST, 45, w * 3, 1.0f);
    dlayer4<1, 1, 1>(w2_1, b2_1, XLs + l, LA + l * ST, 15, w, 1.0f);
    __syncthreads();
    // s2: H 45->30 ; L 15->30
    dlayer4<45, 45, 2>(w1_2, b1_2, HB + l * ST, HA + l * ST, 30, w * 2, 1.0f);
    dlayer4<15, 15, 2>(w2_2, b2_2, LA + l * ST, LB + l * ST, 30, w * 2, 1.0f);
    __syncthreads();
    // dpt copies + Dn = m*Dp + s3 (wa2 30->60)
    for (int i = tid; i < 1920; i += 1024) {
        int r = i / 30, c = i - r * 30;
        dptH[i] = HA[r * ST + c];
        dptL[i] = LB[r * ST + c];
    }
    for (int i = tid; i < 1920; i += 1024) {
        int c = i >> 6, j = i & 63;
        out[OFF3 + i] = mf * HA[j * ST + c];
        out[OFF5 + i] = mf * LB[j * ST + c];
    }
    dlayer4<30, 30, 4>(wa2, ba2, HA + l * ST, HB + l * ST, 60, w * 4, 1.0f);
    dlayer4<30, 30, 4>(wa2, ba2, LB + l * ST, LA + l * ST, 60, w * 4, 1.0f);
    __syncthreads();
    for (int i = tid; i < 3840; i += 1024) {
        int r = i / 60, c = i - r * 60;
        d2H[i] = HB[r * ST + c];
        d2L[i] = LA[r * ST + c];
    }
}

// ---------------- Kernel B: per-item chain (64 items/block, 16 waves, interleaved H+L;
// momentum update fused in when m != 1 — A matrices never leave LDS) ----------------
__global__ __launch_bounds__(1024) void chain_kernel(
    const float* __restrict__ spH, const float* __restrict__ spL,
    const float* __restrict__ dptH, const float* __restrict__ dptL,
    const float* __restrict__ d2H, const float* __restrict__ d2L,
    const float* __restrict__ w1_1, const float* __restrict__ b1_1,
    const float* __restrict__ w1_2, const float* __restrict__ b1_2,
    const float* __restrict__ w2_1, const float* __restrict__ b2_1,
    const float* __restrict__ w2_2, const float* __restrict__ b2_2,
    const float* __restrict__ wa1, const float* __restrict__ ba1,
    const float* __restrict__ wo1, const float* __restrict__ bo1,
    const float* __restrict__ wo2, const float* __restrict__ bo2,
    const int* __restrict__ mI,
    float* __restrict__ out)
{
    __shared__ __align__(16) float HA[64 * ST];
    __shared__ __align__(16) float HB[64 * ST];
    __shared__ __align__(16) float LA[64 * ST];
    __shared__ __align__(16) float LB[64 * ST];
    __shared__ float XLs[64];
    __shared__ float PH[16 * 64], PL[16 * 64];
    __shared__ float INVH[64], INVL[64];

    const int tid = threadIdx.x;
    const int w = __builtin_amdgcn_readfirstlane(tid >> 6);
    const int l = tid & 63;
    const int b0 = blockIdx.x * 64;
    const int b = b0 + l;
    const float mf = (float)(*mI);

    {
        int r = tid >> 4, q = tid & 15;
        *(float4*)(HA + r * ST + 4 * q) = ((const float4*)(spH + (size_t)b0 * 64))[tid];
        if (tid < 64) XLs[tid] = spL[b0 + tid];
    }
    __syncthreads();

    // s1: H 63->45 ; L 1->15
    dlayer4<63, 63, 3>(w1_1, b1_1, HA + l * ST, HB + l * ST, 45, w * 3, 1.0f);
    dlayer4<1, 1, 1>(w2_1, b2_1, XLs + l, LA + l * ST, 15, w, 1.0f);
    __syncthreads();
    // s2: H 45->30 ; L 15->30
    dlayer4<45, 45, 2>(w1_2, b1_2, HB + l * ST, HA + l * ST, 30, w * 2, 1.0f);
    dlayer4<15, 15, 2>(w2_2, b2_2, LA + l * ST, LB + l * ST, 30, w * 2, 1.0f);
    __syncthreads();
    // data copies + s3: 30->60 (wa1) both branches
    for (int i = tid; i < 1920; i += 1024) {
        int r = i / 30, c = i - r * 30;
        out[(size_t)b0 * 30 + i] = HA[r * ST + c];
        out[OFF1 + (size_t)b0 * 30 + i] = LB[r * ST + c];
    }
    dlayer4<30, 30, 4>(wa1, ba1, HA + l * ST, HB + l * ST, 60, w * 4, 1.0f);
    dlayer4<30, 30, 4>(wa1, ba1, LB + l * ST, LA + l * ST, 60, w * 4, 1.0f);
    __syncthreads();
    // s4: S = H1 @ D2^T (60->64) both branches
    dlayer4<60, 60, 4>(d2H, nullptr, HB + l * ST, HA + l * ST, 64, w * 4, 1.0f);
    dlayer4<60, 60, 4>(d2L, nullptr, LA + l * ST, LB + l * ST, 64, w * 4, 1.0f);
    __syncthreads();
    // s5: exp(S - max) both branches
    softmax_exp4(HA + l * ST, HB + l * ST, PH, w, l);
    softmax_exp4(LB + l * ST, LA + l * ST, PL, w, l);
    __syncthreads();
    // fused momentum update (only when m != 1): Dn += (1-m) * data^T @ A.
    // A = exp/sum lives in HB (H) / LA (L); data re-read from this block's own
    // out writes (ordered by the barriers above). mf is block-uniform -> the
    // inner __syncthreads is reached by all threads or none.
    if (mf != 1.0f) {
        if (tid < 64) INVH[tid] = inv16(PH, tid);
        else if (tid < 128) INVL[tid - 64] = inv16(PL, tid - 64);
        __syncthreads();
        const bool isH = w < 8;
        const float* E = isH ? HB : LA;
        const float* INV = isH ? INVH : INVL;
        const float* dat = out + (isH ? 0 : OFF1) + (size_t)b0 * 30;
        float* D = out + (isH ? OFF3 : OFF5);
        const int c0 = (w & 7) * 4;
        float acc[4];
#pragma unroll
        for (int k = 0; k < 4; ++k) acc[k] = 0.f;
        for (int it = 0; it < 64; ++it) {
            const float a = E[it * ST + l] * INV[it];
#pragma unroll
            for (int k = 0; k < 4; ++k) {
                int c = c0 + k; c = c < 30 ? c : 29;
                acc[k] = fmaf(dat[it * 30 + c], a, acc[k]);
            }
        }
        const float s = 1.0f - mf;
#pragma unroll
        for (int k = 0; k < 4; ++k) {
            int c = c0 + k;
            if (c < 30) atomicAdd(&D[c * 64 + l], s * acc[k]);
        }
    }
    {
        const float invH = inv16(PH, l);
        const float invL = inv16(PL, l);
        dlayerT4<64, 30, 2>(dptH, HB + l * ST, HA + l * ST, 30, w * 2, invH);
        dlayerT4<64, 30, 2>(dptL, LA + l * ST, LB + l * ST, 30, w * 2, invL);
    }
    __syncthreads();
    // s8: 30->60 (wa1) both branches
    dlayer4<30, 30, 4>(wa1, ba1, HA + l * ST, HB + l * ST, 60, w * 4, 1.0f);
    dlayer4<30, 30, 4>(wa1, ba1, LB + l * ST, LA + l * ST, 60, w * 4, 1.0f);
    __syncthreads();
    // HSI_A / LiDAR_A copies
    for (int i = tid; i < 3840; i += 1024) {
        int r = i / 60, c = i - r * 60;
        out[OFF2 + (size_t)b0 * 60 + i] = HB[r * ST + c];
        out[OFF4 + (size_t)b0 * 60 + i] = LA[r * ST + c];
    }
    // o1: 120->60 = wo1[:, :60]@A60l + wo1[:, 60:]@A60h (f4 chunked)
    {
        const int o0 = w * 4;
        float acc[4];
#pragma unroll
        for (int k = 0; k < 4; ++k) acc[k] = (o0 + k < 60) ? bo1[o0 + k] : 0.0f;
#pragma unroll
        for (int c0 = 0; c0 < 60; c0 += 16) {
            const int CH = (60 - c0) < 16 ? (60 - c0) : 16;
            float x[16];
            if (CH == 16) load_chunk<16>(LA + l * ST + c0, x);
            else load_chunk<12>(LA + l * ST + c0, x);
#pragma unroll
            for (int k = 0; k < 4; ++k) {
                int oc = o0 + k; oc = oc < 60 ? oc : 59;
                const float* Wr = wo1 + oc * 120 + c0;
                float a = acc[k];
#pragma unroll
                for (int j = 0; j < 16; ++j) if (j < CH) a = fmaf(Wr[j], x[j], a);
                acc[k] = a;
            }
        }
#pragma unroll
        for (int c0 = 0; c0 < 60; c0 += 16) {
            const int CH = (60 - c0) < 16 ? (60 - c0) : 16;
            float x[16];
            if (CH == 16) load_chunk<16>(HB + l * ST + c0, x);
            else load_chunk<12>(HB + l * ST + c0, x);
#pragma unroll
            for (int k = 0; k < 4; ++k) {
                int oc = o0 + k; oc = oc < 60 ? oc : 59;
                const float* Wr = wo1 + oc * 120 + 60 + c0;
                float a = acc[k];
#pragma unroll
                for (int j = 0; j < 16; ++j) if (j < CH) a = fmaf(Wr[j], x[j], a);
                acc[k] = a;
            }
        }
        if (o0 < 60) {
            float4 av; av.x = acc[0]; av.y = acc[1]; av.z = acc[2]; av.w = acc[3];
            *((float4*)(HA + l * ST + o0)) = av;
        }
    }
    __syncthreads();
    // o2: 60->7 (waves 0-6)
    if (w < 7) {
        float a = bo2[w];
        const float* Wr = wo2 + w * 60;
#pragma unroll
        for (int c0 = 0; c0 < 60; c0 += 16) {
            const int CH = (60 - c0) < 16 ? (60 - c0) : 16;
            float x[16];
            if (CH == 16) load_chunk<16>(HA + l * ST + c0, x);
            else load_chunk<12>(HA + l * ST + c0, x);
#pragma unroll
            for (int j = 0; j < 16; ++j) if (j < CH) a = fmaf(Wr[c0 + j], x[j], a);
        }
        out[OFF6 + (size_t)b * 7 + w] = a;
    }
}

extern "C" void kernel_launch(void* const* d_in, const int* in_sizes, int n_in,
                              void* d_out, int out_size, void* d_ws, size_t ws_size,
                              hipStream_t stream) {
    const float* H_HSI        = (const float*)d_in[0];
    const float* H_LiDAR      = (const float*)d_in[1];
    const float* HSI_D        = (const float*)d_in[2];
    const float* LiDAR_D      = (const float*)d_in[3];
    const float* Patch_HSI    = (const float*)d_in[4];
    const float* Patch_LiDAR  = (const float*)d_in[5];
    const float* D_Patch_HSI  = (const float*)d_in[6];
    const float* D_Patch_LiDAR= (const float*)d_in[7];
    const int*   mI           = (const int*)d_in[9];
    const float* w1_1 = (const float*)d_in[12];
    const float* b1_1 = (const float*)d_in[13];
    const float* w1_2 = (const float*)d_in[14];
    const float* b1_2 = (const float*)d_in[15];
    const float* w2_1 = (const float*)d_in[16];
    const float* b2_1 = (const float*)d_in[17];
    const float* w2_2 = (const float*)d_in[18];
    const float* b2_2 = (const float*)d_in[19];
    const float* wa1  = (const float*)d_in[20];
    const float* ba1  = (const float*)d_in[21];
    const float* wa2  = (const float*)d_in[22];
    const float* ba2  = (const float*)d_in[23];
    const float* wo1  = (const float*)d_in[24];
    const float* bo1  = (const float*)d_in[25];
    const float* wo2  = (const float*)d_in[26];
    const float* bo2  = (const float*)d_in[27];

    float* out = (float*)d_out;
    float* ws  = (float*)d_ws;

    patch_attend_kernel<<<NB / 4 + DN / 4, 256, 0, stream>>>(
        Patch_HSI, H_HSI, Patch_LiDAR, H_LiDAR, ws + SPH_OFF, ws + SPL_OFF,
        D_Patch_HSI, HSI_D, D_Patch_LiDAR, LiDAR_D, ws + DSPH_OFF, ws + DSPL_OFF);
    dict_chain_kernel<<<1, 1024, 0, stream>>>(
        ws + DSPH_OFF, ws + DSPL_OFF,
        w1_1, b1_1, w1_2, b1_2, w2_1, b2_1, w2_2, b2_2, wa2, ba2,
        ws + DPTH_OFF, ws + DPTL_OFF, ws + D2H_OFF, ws + D2L_OFF, mI, out);
    chain_kernel<<<NB / 64, 1024, 0, stream>>>(
        ws + SPH_OFF, ws + SPL_OFF,
        ws + DPTH_OFF, ws + DPTL_OFF, ws + D2H_OFF, ws + D2L_OFF,
        w1_1, b1_1, w1_2, b1_2, w2_1, b2_1, w2_2, b2_2,
        wa1, ba1, wo1, bo1, wo2, bo2, mI, out);
}